// Round 16
// baseline (189.007 us; speedup 1.0000x reference)
//
#include <hip/hip_runtime.h>

typedef __bf16 bf16;
typedef __attribute__((ext_vector_type(8))) __bf16 bf16x8;
typedef __attribute__((ext_vector_type(4))) __bf16 bf16x4;
typedef __attribute__((ext_vector_type(4))) float f32x4;

constexpr int T_SEQ = 2048;
constexpr int DIM   = 2048;
constexpr int NH    = 32;
constexpr int NKV   = 8;
constexpr int HD    = 64;
constexpr int QKV_N = DIM + 2 * NKV * HD;   // 3072
constexpr int MROWS = 2 * T_SEQ;            // 4096 (B*T)

// ---------------- fused cast: x -> xb, wq|wk|wv -> wqkv, wo -> wob ----------------
__global__ void cast_all_kernel(const float* __restrict__ x,
                                const float* __restrict__ wq, const float* __restrict__ wk,
                                const float* __restrict__ wv, const float* __restrict__ wo,
                                bf16* __restrict__ xb, bf16* __restrict__ wqkv,
                                bf16* __restrict__ wob) {
  int stride = gridDim.x * blockDim.x;
  for (int g = blockIdx.x * blockDim.x + threadIdx.x; g < 4718592; g += stride) {
    const float* src; bf16* dst; int off;
    if (g < 2097152)      { src = x;  dst = xb;             off = g; }
    else if (g < 3145728) { src = wq; dst = wqkv;           off = g - 2097152; }
    else if (g < 3407872) { src = wk; dst = wqkv + 4194304; off = g - 3145728; }
    else if (g < 3670016) { src = wv; dst = wqkv + 5242880; off = g - 3407872; }
    else                  { src = wo; dst = wob;            off = g - 3670016; }
    float4 v = *(const float4*)(src + (size_t)off * 4);
    bf16x4 o = { (bf16)v.x, (bf16)v.y, (bf16)v.z, (bf16)v.w };
    *(bf16x4*)(dst + (size_t)off * 4) = o;
  }
}

// ---------------- GEMM: C[m][n] = sum_k A[m][k] * W[n][k] ----------------
// 3-deep LDS ring, prefetch depth 2, counted vmcnt at tile top (T4), XOR-swz
// LDS (T2) via pre-swizzled global source, setprio'd MFMA cluster (T5).
// BM=256: 8 waves 4Mx2N (out-proj, 256 blocks perfect fill).
// BM=128: 8 waves 2Mx4N-of-32 (QKV: 768 blocks = 3 exact rounds, perfect fill).
template <typename OutT, int BM>
__global__ __launch_bounds__(512) void gemm256(const bf16* __restrict__ A,
                                               const bf16* __restrict__ W,
                                               OutT* __restrict__ C,
                                               int N, int K, int cpx) {
  constexpr int BN = 128, BK = 64;
  constexpr int AISS = BM / 64;             // A stage issues per thread
  constexpr int NI = (BM == 256) ? 4 : 2;   // N-frags per wave
  __shared__ __attribute__((aligned(16))) bf16 Ab[3][BM * BK];
  __shared__ __attribute__((aligned(16))) bf16 Bb[3][BN * BK];
  const int tid = threadIdx.x, lane = tid & 63, wave = tid >> 6;
  const int l15 = lane & 15, l4 = lane >> 4;
  const int orig = blockIdx.x;
  const int wg = (orig & 7) * cpx + (orig >> 3);   // XCD chunking (nwg % 8 == 0)
  const int bm = (BM == 256) ? (wg & 15) * 256 : (wg & 31) * 128;
  const int bn = (BM == 256) ? (wg >> 4) * BN : (wg >> 5) * BN;
  const int wm = (BM == 256) ? (wave >> 1) * 64 : (wave >> 2) * 64;
  const int wn = (BM == 256) ? (wave & 1) * 64 : (wave & 3) * 32;

  f32x4 acc[4][NI] = {};

  const int NT = K / BK;
  auto stage = [&](int s, int k0) {
    #pragma unroll
    for (int i = 0; i < AISS; ++i) {               // A: BM x 64
      int c = i * 512 + tid;
      int row = c >> 3;
      int gc = ((c & 7) ^ (row & 7)) << 3;
      __builtin_amdgcn_global_load_lds(
          (const __attribute__((address_space(1))) unsigned int*)(A + (size_t)(bm + row) * K + k0 + gc),
          (__attribute__((address_space(3))) unsigned int*)(&Ab[s][0] + c * 8), 16, 0, 0);
    }
    #pragma unroll
    for (int i = 0; i < 2; ++i) {                  // B: 128 x 64
      int c = i * 512 + tid;
      int row = c >> 3;
      int gc = ((c & 7) ^ (row & 7)) << 3;
      __builtin_amdgcn_global_load_lds(
          (const __attribute__((address_space(1))) unsigned int*)(W + (size_t)(bn + row) * K + k0 + gc),
          (__attribute__((address_space(3))) unsigned int*)(&Bb[s][0] + c * 8), 16, 0, 0);
    }
  };

  stage(0, 0);
  stage(1, BK);

  int d = 0;
  for (int t = 0; t < NT; ++t) {
    // tile top: newest stage may stay in flight; oldest must have landed.
    if (t + 1 < NT) {
      if constexpr (BM == 256) { asm volatile("s_waitcnt vmcnt(6)" ::: "memory"); }
      else                     { asm volatile("s_waitcnt vmcnt(4)" ::: "memory"); }
    } else {
      asm volatile("s_waitcnt vmcnt(0)" ::: "memory");
    }
    __builtin_amdgcn_s_barrier();

    bf16x8 af[2][4], bfr[2][NI];
    #pragma unroll
    for (int kk = 0; kk < 2; ++kk) {
      #pragma unroll
      for (int mi = 0; mi < 4; ++mi) {
        int row = wm + mi * 16 + l15;
        af[kk][mi] = *(const bf16x8*)((const char*)&Ab[d][0] + row * 128 +
                                      (((kk * 4 + l4) ^ (row & 7)) << 4));
      }
      #pragma unroll
      for (int ni = 0; ni < NI; ++ni) {
        int row = wn + ni * 16 + l15;
        bfr[kk][ni] = *(const bf16x8*)((const char*)&Bb[d][0] + row * 128 +
                                       (((kk * 4 + l4) ^ (row & 7)) << 4));
      }
    }

    if (t + 2 < NT) {
      int s = d + 2; if (s >= 3) s -= 3;
      stage(s, (t + 2) * BK);
    }

    __builtin_amdgcn_s_setprio(1);
    #pragma unroll
    for (int kk = 0; kk < 2; ++kk)
      #pragma unroll
      for (int mi = 0; mi < 4; ++mi)
        #pragma unroll
        for (int ni = 0; ni < NI; ++ni)
          acc[mi][ni] = __builtin_amdgcn_mfma_f32_16x16x32_bf16(af[kk][mi], bfr[kk][ni],
                                                                acc[mi][ni], 0, 0, 0);
    __builtin_amdgcn_s_setprio(0);

    ++d; if (d == 3) d = 0;
  }

  #pragma unroll
  for (int mi = 0; mi < 4; ++mi)
    #pragma unroll
    for (int ni = 0; ni < NI; ++ni) {
      size_t row = (size_t)bm + wm + mi * 16 + l4 * 4;
      int col = bn + wn + ni * 16 + l15;
      #pragma unroll
      for (int r = 0; r < 4; ++r)
        C[(row + r) * N + col] = (OutT)acc[mi][ni][r];
    }
}

// ---------------- RoPE, vectorized (unchanged) ----------------
__global__ void rope_kernel(bf16* __restrict__ qkv, const float* __restrict__ cs,
                            const float* __restrict__ sn) {
  int idx = blockIdx.x * blockDim.x + threadIdx.x;
  int m = idx / 160;
  int ch = idx - m * 160;
  int t = m & (T_SEQ - 1);
  int col, c;
  if (ch < 128) { int hh = ch >> 2; c = ch & 3; col = hh * 64 + c * 16; }
  else          { int ch2 = ch - 128; int hh = ch2 >> 2; c = ch2 & 3; col = DIM + hh * 64 + c * 16; }
  bf16* ptr = qkv + (size_t)m * QKV_N + col;
  bf16x8 v0 = *(bf16x8*)ptr, v1 = *(bf16x8*)(ptr + 8);
  const float* cp = cs + t * 32 + c * 8;
  const float* sp = sn + t * 32 + c * 8;
  float4 c0 = *(const float4*)cp, c1 = *(const float4*)(cp + 4);
  float4 s0 = *(const float4*)sp, s1 = *(const float4*)(sp + 4);
  float cc[8] = {c0.x, c0.y, c0.z, c0.w, c1.x, c1.y, c1.z, c1.w};
  float ss[8] = {s0.x, s0.y, s0.z, s0.w, s1.x, s1.y, s1.z, s1.w};
  bf16x8 o0, o1;
  #pragma unroll
  for (int j = 0; j < 4; ++j) {
    float a = (float)v0[2 * j], b = (float)v0[2 * j + 1];
    o0[2 * j]     = (bf16)(a * cc[j] - b * ss[j]);
    o0[2 * j + 1] = (bf16)(a * ss[j] + b * cc[j]);
  }
  #pragma unroll
  for (int j = 0; j < 4; ++j) {
    float a = (float)v1[2 * j], b = (float)v1[2 * j + 1];
    o1[2 * j]     = (bf16)(a * cc[4 + j] - b * ss[4 + j]);
    o1[2 * j + 1] = (bf16)(a * ss[4 + j] + b * cc[4 + j]);
  }
  *(bf16x8*)ptr = o0;
  *(bf16x8*)(ptr + 8) = o1;
}

// ---------------- Flash attention, causal GQA (unchanged from R15) ----------------
__global__ __launch_bounds__(512, 2) void attn_kernel(const bf16* __restrict__ qkv,
                                                      bf16* __restrict__ y) {
  const int h = blockIdx.x, b = blockIdx.z;
  const int strip = 15 - blockIdx.y;              // longest-first (LPT w/ backfill)
  const int g = h >> 2;
  const int tid = threadIdx.x, lane = tid & 63, wave = tid >> 6;
  const int l15 = lane & 15, l4 = lane >> 4;
  const int qbase = strip * 128 + wave * 16;

  __shared__ __attribute__((aligned(16))) bf16 Kb[2][128 * 64];  // [kv][d], swizzled, dbuf
  __shared__ __attribute__((aligned(16))) bf16 VTs[2][64 * 64];  // [d][kv] per half, swizzled
  __shared__ __attribute__((aligned(16))) bf16 Pb[8][16 * 64];   // per-wave [q][kv], swizzled

  constexpr float SCALE2 = 0.125f * 1.44269504088896f;
  constexpr float THR_RAW = 8.0f / SCALE2;
  constexpr int VOFF = DIM + NKV * HD;

  bf16x8 qf[2];
  {
    const bf16* qp = qkv + ((size_t)b * T_SEQ + qbase + l15) * QKV_N + h * HD + l4 * 8;
    qf[0] = *(const bf16x8*)(qp);
    qf[1] = *(const bf16x8*)(qp + 32);
  }

  f32x4 oacc[4] = {};
  float m_run = -INFINITY, l_run = 0.f;
  const int qg = qbase + l15;

  const int nt = strip + 1;                 // 128-kv tiles
  const size_t kvbase = (size_t)b * T_SEQ;

  // ---- prologue: K tile0 (2 glds) -> Kb[0]; V tile0 halves -> VTs ----
  {
    #pragma unroll
    for (int i = 0; i < 2; ++i) {
      int chunk = i * 512 + tid;
      int row = chunk >> 3;
      int csrc = ((chunk & 7) << 3) ^ ((row & 7) << 3);
      __builtin_amdgcn_global_load_lds(
          (const __attribute__((address_space(1))) unsigned int*)
              (qkv + (kvbase + row) * QKV_N + DIM + g * HD + csrc),
          (__attribute__((address_space(3))) unsigned int*)(&Kb[0][0] + chunk * 8), 16, 0, 0);
    }
    #pragma unroll
    for (int hf = 0; hf < 2; ++hf) {
      const bf16* vp = qkv + (kvbase + hf * 64 + wave * 8) * QKV_N + VOFF + g * HD + lane;
      bf16x8 vr;
      #pragma unroll
      for (int j = 0; j < 8; ++j) vr[j] = vp[(size_t)j * QKV_N];
      *(bf16x8*)((char*)&VTs[hf][0] + ((lane * 128 + wave * 16) ^ ((lane & 7) << 4))) = vr;
    }
    asm volatile("s_waitcnt vmcnt(0)" ::: "memory");
    __syncthreads();
  }

  int cur = 0;
  for (int kt = 0; kt < nt; ++kt) {
    const bool has_next = (kt + 1) < nt;
    bf16x8 vr0, vr1;
    if (has_next) {
      #pragma unroll
      for (int i = 0; i < 2; ++i) {
        int chunk = i * 512 + tid;
        int row = chunk >> 3;
        int csrc = ((chunk & 7) << 3) ^ ((row & 7) << 3);
        __builtin_amdgcn_global_load_lds(
            (const __attribute__((address_space(1))) unsigned int*)
                (qkv + (kvbase + (kt + 1) * 128 + row) * QKV_N + DIM + g * HD + csrc),
            (__attribute__((address_space(3))) unsigned int*)(&Kb[cur ^ 1][0] + chunk * 8), 16, 0, 0);
      }
      const bf16* vp0 = qkv + (kvbase + (kt + 1) * 128 + wave * 8) * QKV_N + VOFF + g * HD + lane;
      const bf16* vp1 = vp0 + (size_t)64 * QKV_N;
      #pragma unroll
      for (int j = 0; j < 8; ++j) vr0[j] = vp0[(size_t)j * QKV_N];
      #pragma unroll
      for (int j = 0; j < 8; ++j) vr1[j] = vp1[(size_t)j * QKV_N];
    }

    const bf16* kb = &Kb[cur][0];
    const bool diag = (kt == strip);

    #pragma unroll
    for (int hf = 0; hf < 2; ++hf) {
      if (diag && hf == 1 && wave < 4) continue;   // fully-masked upper half

      f32x4 z[4];
      #pragma unroll
      for (int nt4 = 0; nt4 < 4; ++nt4) z[nt4] = (f32x4){0.f, 0.f, 0.f, 0.f};
      #pragma unroll
      for (int nt4 = 0; nt4 < 4; ++nt4)
        #pragma unroll
        for (int kk = 0; kk < 2; ++kk) {
          bf16x8 kf = *(const bf16x8*)((const char*)kb +
              (((hf * 64 + nt4 * 16 + l15) * 128 + (kk * 32 + l4 * 8) * 2) ^ ((l15 & 7) << 4)));
          z[nt4] = __builtin_amdgcn_mfma_f32_16x16x32_bf16(kf, qf[kk], z[nt4], 0, 0, 0);
        }

      if (diag) {
        #pragma unroll
        for (int nt4 = 0; nt4 < 4; ++nt4)
          #pragma unroll
          for (int r = 0; r < 4; ++r)
            if (kt * 128 + hf * 64 + nt4 * 16 + l4 * 4 + r > qg) z[nt4][r] = -INFINITY;
      }

      float vm = z[0][0];
      #pragma unroll
      for (int nt4 = 0; nt4 < 4; ++nt4)
        #pragma unroll
        for (int r = 0; r < 4; ++r) vm = fmaxf(vm, z[nt4][r]);
      vm = fmaxf(vm, __shfl_xor(vm, 16));
      vm = fmaxf(vm, __shfl_xor(vm, 32));

      if (!__all(vm - m_run <= THR_RAW)) {
        float mnew = fmaxf(m_run, vm);
        float alpha = __builtin_amdgcn_exp2f((m_run - mnew) * SCALE2);
        l_run *= alpha;
        #pragma unroll
        for (int dt = 0; dt < 4; ++dt)
          #pragma unroll
          for (int r = 0; r < 4; ++r) oacc[dt][r] *= alpha;
        m_run = mnew;
      }
      const float ms = m_run * SCALE2;

      float ps = 0.f;
      #pragma unroll
      for (int nt4 = 0; nt4 < 4; ++nt4)
        #pragma unroll
        for (int r = 0; r < 4; ++r) {
          float pv = __builtin_amdgcn_exp2f(__builtin_fmaf(z[nt4][r], SCALE2, -ms));
          z[nt4][r] = pv;
          ps += pv;
        }
      ps += __shfl_xor(ps, 16);
      ps += __shfl_xor(ps, 32);
      l_run += ps;

      bf16* pbw = &Pb[wave][0];
      #pragma unroll
      for (int nt4 = 0; nt4 < 4; ++nt4) {
        bf16x4 pk = { (bf16)z[nt4][0], (bf16)z[nt4][1], (bf16)z[nt4][2], (bf16)z[nt4][3] };
        *(bf16x4*)((char*)pbw + ((l15 * 128 + nt4 * 32 + l4 * 8) ^ ((l15 & 7) << 4))) = pk;
      }

      const bf16* vt = &VTs[hf][0];
      #pragma unroll
      for (int kk = 0; kk < 2; ++kk) {
        bf16x8 pf = *(const bf16x8*)((const char*)pbw +
            ((l15 * 128 + kk * 64 + l4 * 16) ^ ((l15 & 7) << 4)));
        #pragma unroll
        for (int dt = 0; dt < 4; ++dt) {
          bf16x8 vf = *(const bf16x8*)((const char*)vt +
              (((dt * 16 + l15) * 128 + (kk * 32 + l4 * 8) * 2) ^ ((l15 & 7) << 4)));
          oacc[dt] = __builtin_amdgcn_mfma_f32_16x16x32_bf16(vf, pf, oacc[dt], 0, 0, 0);
        }
      }
    }

    if (has_next) {
      __syncthreads();   // all waves done reading VTs (also drains K glds)
      *(bf16x8*)((char*)&VTs[0][0] + ((lane * 128 + wave * 16) ^ ((lane & 7) << 4))) = vr0;
      *(bf16x8*)((char*)&VTs[1][0] + ((lane * 128 + wave * 16) ^ ((lane & 7) << 4))) = vr1;
      __syncthreads();   // VTs(t+1) visible; Kb[cur^1] landed
      cur ^= 1;
    }
  }

  {
    float linv = __builtin_amdgcn_rcpf(l_run);
    bf16* yp = y + ((size_t)b * T_SEQ + qbase + l15) * DIM + h * HD + l4 * 4;
    #pragma unroll
    for (int dt = 0; dt < 4; ++dt) {
      bf16x4 ov = { (bf16)(oacc[dt][0] * linv), (bf16)(oacc[dt][1] * linv),
                    (bf16)(oacc[dt][2] * linv), (bf16)(oacc[dt][3] * linv) };
      *(bf16x4*)(yp + dt * 16) = ov;
    }
  }
}

// ---------------- launch ----------------
extern "C" void kernel_launch(void* const* d_in, const int* in_sizes, int n_in,
                              void* d_out, int out_size, void* d_ws, size_t ws_size,
                              hipStream_t stream) {
  const float* x    = (const float*)d_in[0];
  const float* cosb = (const float*)d_in[1];
  const float* sinb = (const float*)d_in[2];
  const float* wq   = (const float*)d_in[3];
  const float* wk   = (const float*)d_in[4];
  const float* wv   = (const float*)d_in[5];
  const float* wo   = (const float*)d_in[6];
  float* out = (float*)d_out;

  bf16* xb   = (bf16*)d_ws;                           // 4096*2048
  bf16* wqkv = xb + (size_t)MROWS * DIM;              // 3072*2048
  bf16* wob  = wqkv + (size_t)QKV_N * DIM;            // 2048*2048
  bf16* qkv  = wob + (size_t)DIM * DIM;               // 4096*3072
  bf16* y    = qkv + (size_t)MROWS * QKV_N;           // 4096*2048

  // fused casts (one launch)
  cast_all_kernel<<<2048, 256, 0, stream>>>(x, wq, wk, wv, wo, xb, wqkv, wob);

  // QKV projection: M=4096, N=3072, K=2048 -> BM=128: 32x24 = 768 blocks (3 exact rounds)
  gemm256<bf16, 128><<<768, 512, 0, stream>>>(xb, wqkv, qkv, QKV_N, DIM, 768 / 8);

  // RoPE on q,k
  rope_kernel<<<(MROWS * 160) / 256, 256, 0, stream>>>(qkv, cosb, sinb);

  // attention: one 128-row strip per block, KVBLK=128 (unchanged R15)
  attn_kernel<<<dim3(NH, 16, 2), 512, 0, stream>>>(qkv, y);

  // output projection: M=4096, N=2048, K=2048 -> BM=256: 256 blocks (1 exact round)
  gemm256<float, 256><<<256, 512, 0, stream>>>(y, wob, out, DIM, DIM, 256 / 8);
}

// Round 17
// 185.165 us; speedup vs baseline: 1.0207x; 1.0207x over previous
//
#include <hip/hip_runtime.h>

typedef __bf16 bf16;
typedef __attribute__((ext_vector_type(8))) __bf16 bf16x8;
typedef __attribute__((ext_vector_type(4))) __bf16 bf16x4;
typedef __attribute__((ext_vector_type(4))) float f32x4;

constexpr int T_SEQ = 2048;
constexpr int DIM   = 2048;
constexpr int NH    = 32;
constexpr int NKV   = 8;
constexpr int HD    = 64;
constexpr int QKV_N = DIM + 2 * NKV * HD;   // 3072
constexpr int MROWS = 2 * T_SEQ;            // 4096 (B*T)

// ---------------- fused cast: x -> xb, wq|wk|wv -> wqkv, wo -> wob ----------------
__global__ void cast_all_kernel(const float* __restrict__ x,
                                const float* __restrict__ wq, const float* __restrict__ wk,
                                const float* __restrict__ wv, const float* __restrict__ wo,
                                bf16* __restrict__ xb, bf16* __restrict__ wqkv,
                                bf16* __restrict__ wob) {
  int stride = gridDim.x * blockDim.x;
  for (int g = blockIdx.x * blockDim.x + threadIdx.x; g < 4718592; g += stride) {
    const float* src; bf16* dst; int off;
    if (g < 2097152)      { src = x;  dst = xb;             off = g; }
    else if (g < 3145728) { src = wq; dst = wqkv;           off = g - 2097152; }
    else if (g < 3407872) { src = wk; dst = wqkv + 4194304; off = g - 3145728; }
    else if (g < 3670016) { src = wv; dst = wqkv + 5242880; off = g - 3407872; }
    else                  { src = wo; dst = wob;            off = g - 3670016; }
    float4 v = *(const float4*)(src + (size_t)off * 4);
    bf16x4 o = { (bf16)v.x, (bf16)v.y, (bf16)v.z, (bf16)v.w };
    *(bf16x4*)(dst + (size_t)off * 4) = o;
  }
}

// ---------------- GEMM (R11/R15 proven: BM=256, 3-deep ring, vmcnt(6)) ----------------
template <typename OutT>
__global__ __launch_bounds__(512) void gemm256(const bf16* __restrict__ A,
                                               const bf16* __restrict__ W,
                                               OutT* __restrict__ C,
                                               int N, int K, int cpx) {
  constexpr int BM = 256, BN = 128, BK = 64;
  __shared__ __attribute__((aligned(16))) bf16 Ab[3][BM * BK];
  __shared__ __attribute__((aligned(16))) bf16 Bb[3][BN * BK];
  const int tid = threadIdx.x, lane = tid & 63, wave = tid >> 6;
  const int l15 = lane & 15, l4 = lane >> 4;
  const int orig = blockIdx.x;
  const int wg = (orig & 7) * cpx + (orig >> 3);   // XCD chunking (nwg % 8 == 0)
  const int bm = (wg & 15) * BM;                   // M/256 == 16
  const int bn = (wg >> 4) * BN;                   // bn-major
  const int wm = (wave >> 1) * 64, wn = (wave & 1) * 64;

  f32x4 acc[4][4] = {};

  const int NT = K / BK;
  auto stage = [&](int s, int k0) {
    #pragma unroll
    for (int i = 0; i < 4; ++i) {
      int c = i * 512 + tid;
      int row = c >> 3;
      int gc = ((c & 7) ^ (row & 7)) << 3;
      __builtin_amdgcn_global_load_lds(
          (const __attribute__((address_space(1))) unsigned int*)(A + (size_t)(bm + row) * K + k0 + gc),
          (__attribute__((address_space(3))) unsigned int*)(&Ab[s][0] + c * 8), 16, 0, 0);
    }
    #pragma unroll
    for (int i = 0; i < 2; ++i) {
      int c = i * 512 + tid;
      int row = c >> 3;
      int gc = ((c & 7) ^ (row & 7)) << 3;
      __builtin_amdgcn_global_load_lds(
          (const __attribute__((address_space(1))) unsigned int*)(W + (size_t)(bn + row) * K + k0 + gc),
          (__attribute__((address_space(3))) unsigned int*)(&Bb[s][0] + c * 8), 16, 0, 0);
    }
  };

  stage(0, 0);
  stage(1, BK);

  int d = 0;
  for (int t = 0; t < NT; ++t) {
    if (t + 1 < NT) { asm volatile("s_waitcnt vmcnt(6)" ::: "memory"); }
    else            { asm volatile("s_waitcnt vmcnt(0)" ::: "memory"); }
    __builtin_amdgcn_s_barrier();

    bf16x8 af[2][4], bfr[2][4];
    #pragma unroll
    for (int kk = 0; kk < 2; ++kk) {
      #pragma unroll
      for (int mi = 0; mi < 4; ++mi) {
        int row = wm + mi * 16 + l15;
        af[kk][mi] = *(const bf16x8*)((const char*)&Ab[d][0] + row * 128 +
                                      (((kk * 4 + l4) ^ (row & 7)) << 4));
      }
      #pragma unroll
      for (int ni = 0; ni < 4; ++ni) {
        int row = wn + ni * 16 + l15;
        bfr[kk][ni] = *(const bf16x8*)((const char*)&Bb[d][0] + row * 128 +
                                       (((kk * 4 + l4) ^ (row & 7)) << 4));
      }
    }

    if (t + 2 < NT) {
      int s = d + 2; if (s >= 3) s -= 3;
      stage(s, (t + 2) * BK);
    }

    __builtin_amdgcn_s_setprio(1);
    #pragma unroll
    for (int kk = 0; kk < 2; ++kk)
      #pragma unroll
      for (int mi = 0; mi < 4; ++mi)
        #pragma unroll
        for (int ni = 0; ni < 4; ++ni)
          acc[mi][ni] = __builtin_amdgcn_mfma_f32_16x16x32_bf16(af[kk][mi], bfr[kk][ni],
                                                                acc[mi][ni], 0, 0, 0);
    __builtin_amdgcn_s_setprio(0);

    ++d; if (d == 3) d = 0;
  }

  #pragma unroll
  for (int mi = 0; mi < 4; ++mi)
    #pragma unroll
    for (int ni = 0; ni < 4; ++ni) {
      size_t row = (size_t)bm + wm + mi * 16 + l4 * 4;
      int col = bn + wn + ni * 16 + l15;
      #pragma unroll
      for (int r = 0; r < 4; ++r)
        C[(row + r) * N + col] = (OutT)acc[mi][ni][r];
    }
}

// ---------------- RoPE, vectorized (unchanged) ----------------
__global__ void rope_kernel(bf16* __restrict__ qkv, const float* __restrict__ cs,
                            const float* __restrict__ sn) {
  int idx = blockIdx.x * blockDim.x + threadIdx.x;
  int m = idx / 160;
  int ch = idx - m * 160;
  int t = m & (T_SEQ - 1);
  int col, c;
  if (ch < 128) { int hh = ch >> 2; c = ch & 3; col = hh * 64 + c * 16; }
  else          { int ch2 = ch - 128; int hh = ch2 >> 2; c = ch2 & 3; col = DIM + hh * 64 + c * 16; }
  bf16* ptr = qkv + (size_t)m * QKV_N + col;
  bf16x8 v0 = *(bf16x8*)ptr, v1 = *(bf16x8*)(ptr + 8);
  const float* cp = cs + t * 32 + c * 8;
  const float* sp = sn + t * 32 + c * 8;
  float4 c0 = *(const float4*)cp, c1 = *(const float4*)(cp + 4);
  float4 s0 = *(const float4*)sp, s1 = *(const float4*)(sp + 4);
  float cc[8] = {c0.x, c0.y, c0.z, c0.w, c1.x, c1.y, c1.z, c1.w};
  float ss[8] = {s0.x, s0.y, s0.z, s0.w, s1.x, s1.y, s1.z, s1.w};
  bf16x8 o0, o1;
  #pragma unroll
  for (int j = 0; j < 4; ++j) {
    float a = (float)v0[2 * j], b = (float)v0[2 * j + 1];
    o0[2 * j]     = (bf16)(a * cc[j] - b * ss[j]);
    o0[2 * j + 1] = (bf16)(a * ss[j] + b * cc[j]);
  }
  #pragma unroll
  for (int j = 0; j < 4; ++j) {
    float a = (float)v1[2 * j], b = (float)v1[2 * j + 1];
    o1[2 * j]     = (bf16)(a * cc[4 + j] - b * ss[4 + j]);
    o1[2 * j + 1] = (bf16)(a * ss[4 + j] + b * cc[4 + j]);
  }
  *(bf16x8*)ptr = o0;
  *(bf16x8*)(ptr + 8) = o1;
}

// ---------------- Flash attention, causal GQA ----------------
// grid (NH, 16, B); 512 thr = 8 waves x 16 q-rows = ONE 128-row strip/block.
// KVBLK=128, K dbuf (glds) + VTs NOW DOUBLE-BUFFERED (reg-gather, write into
// the non-read side) -> ONE barrier per 128-kv tile (R15 had 2, R13 had 4).
// LDS 80KB -> 2 blocks/CU. Waves 0-3 skip the masked upper diag half.
__global__ __launch_bounds__(512, 2) void attn_kernel(const bf16* __restrict__ qkv,
                                                      bf16* __restrict__ y) {
  const int h = blockIdx.x, b = blockIdx.z;
  const int strip = 15 - blockIdx.y;              // longest-first
  const int g = h >> 2;
  const int tid = threadIdx.x, lane = tid & 63, wave = tid >> 6;
  const int l15 = lane & 15, l4 = lane >> 4;
  const int qbase = strip * 128 + wave * 16;

  __shared__ __attribute__((aligned(16))) bf16 Kb[2][128 * 64];    // [kv][d], swz, dbuf
  __shared__ __attribute__((aligned(16))) bf16 VTs[2][2][64 * 64]; // [buf][half][d][kv], swz
  __shared__ __attribute__((aligned(16))) bf16 Pb[8][16 * 64];     // per-wave [q][kv], swz

  constexpr float SCALE2 = 0.125f * 1.44269504088896f;
  constexpr float THR_RAW = 8.0f / SCALE2;
  constexpr int VOFF = DIM + NKV * HD;

  bf16x8 qf[2];
  {
    const bf16* qp = qkv + ((size_t)b * T_SEQ + qbase + l15) * QKV_N + h * HD + l4 * 8;
    qf[0] = *(const bf16x8*)(qp);
    qf[1] = *(const bf16x8*)(qp + 32);
  }

  f32x4 oacc[4] = {};
  float m_run = -INFINITY, l_run = 0.f;
  const int qg = qbase + l15;

  const int nt = strip + 1;                 // 128-kv tiles
  const size_t kvbase = (size_t)b * T_SEQ;
  const int vwoff = ((lane * 128 + wave * 16) ^ ((lane & 7) << 4));  // VTs write slot

  // ---- prologue: K tile0 -> Kb[0]; V tile0 halves -> VTs[0] ----
  {
    #pragma unroll
    for (int i = 0; i < 2; ++i) {
      int chunk = i * 512 + tid;
      int row = chunk >> 3;
      int csrc = ((chunk & 7) << 3) ^ ((row & 7) << 3);
      __builtin_amdgcn_global_load_lds(
          (const __attribute__((address_space(1))) unsigned int*)
              (qkv + (kvbase + row) * QKV_N + DIM + g * HD + csrc),
          (__attribute__((address_space(3))) unsigned int*)(&Kb[0][0] + chunk * 8), 16, 0, 0);
    }
    #pragma unroll
    for (int hf = 0; hf < 2; ++hf) {
      const bf16* vp = qkv + (kvbase + hf * 64 + wave * 8) * QKV_N + VOFF + g * HD + lane;
      bf16x8 vr;
      #pragma unroll
      for (int j = 0; j < 8; ++j) vr[j] = vp[(size_t)j * QKV_N];
      *(bf16x8*)((char*)&VTs[0][hf][0] + vwoff) = vr;
    }
    asm volatile("s_waitcnt vmcnt(0)" ::: "memory");
    __syncthreads();
  }

  int cur = 0;
  for (int kt = 0; kt < nt; ++kt) {
    const bool has_next = (kt + 1) < nt;
    bf16x8 vr0, vr1;
    if (has_next) {
      // issue next K tile (async -> Kb[cur^1]; its readers retired at last barrier)
      #pragma unroll
      for (int i = 0; i < 2; ++i) {
        int chunk = i * 512 + tid;
        int row = chunk >> 3;
        int csrc = ((chunk & 7) << 3) ^ ((row & 7) << 3);
        __builtin_amdgcn_global_load_lds(
            (const __attribute__((address_space(1))) unsigned int*)
                (qkv + (kvbase + (kt + 1) * 128 + row) * QKV_N + DIM + g * HD + csrc),
            (__attribute__((address_space(3))) unsigned int*)(&Kb[cur ^ 1][0] + chunk * 8), 16, 0, 0);
      }
      // issue next V gathers (regs)
      const bf16* vp0 = qkv + (kvbase + (kt + 1) * 128 + wave * 8) * QKV_N + VOFF + g * HD + lane;
      const bf16* vp1 = vp0 + (size_t)64 * QKV_N;
      #pragma unroll
      for (int j = 0; j < 8; ++j) vr0[j] = vp0[(size_t)j * QKV_N];
      #pragma unroll
      for (int j = 0; j < 8; ++j) vr1[j] = vp1[(size_t)j * QKV_N];
    }

    const bf16* kb = &Kb[cur][0];
    const bool diag = (kt == strip);

    #pragma unroll
    for (int hf = 0; hf < 2; ++hf) {
      if (diag && hf == 1 && wave < 4) continue;   // fully-masked upper half

      // ---- S^T = K Q^T : z[nt4], lane = (q=l15, k=hf*64+nt4*16+l4*4+r), RAW ----
      f32x4 z[4];
      #pragma unroll
      for (int nt4 = 0; nt4 < 4; ++nt4) z[nt4] = (f32x4){0.f, 0.f, 0.f, 0.f};
      #pragma unroll
      for (int nt4 = 0; nt4 < 4; ++nt4)
        #pragma unroll
        for (int kk = 0; kk < 2; ++kk) {
          bf16x8 kf = *(const bf16x8*)((const char*)kb +
              (((hf * 64 + nt4 * 16 + l15) * 128 + (kk * 32 + l4 * 8) * 2) ^ ((l15 & 7) << 4)));
          z[nt4] = __builtin_amdgcn_mfma_f32_16x16x32_bf16(kf, qf[kk], z[nt4], 0, 0, 0);
        }

      if (diag) {
        #pragma unroll
        for (int nt4 = 0; nt4 < 4; ++nt4)
          #pragma unroll
          for (int r = 0; r < 4; ++r)
            if (kt * 128 + hf * 64 + nt4 * 16 + l4 * 4 + r > qg) z[nt4][r] = -INFINITY;
      }

      float vm = z[0][0];
      #pragma unroll
      for (int nt4 = 0; nt4 < 4; ++nt4)
        #pragma unroll
        for (int r = 0; r < 4; ++r) vm = fmaxf(vm, z[nt4][r]);
      vm = fmaxf(vm, __shfl_xor(vm, 16));
      vm = fmaxf(vm, __shfl_xor(vm, 32));

      if (!__all(vm - m_run <= THR_RAW)) {
        float mnew = fmaxf(m_run, vm);
        float alpha = __builtin_amdgcn_exp2f((m_run - mnew) * SCALE2);
        l_run *= alpha;
        #pragma unroll
        for (int dt = 0; dt < 4; ++dt)
          #pragma unroll
          for (int r = 0; r < 4; ++r) oacc[dt][r] *= alpha;
        m_run = mnew;
      }
      const float ms = m_run * SCALE2;

      float ps = 0.f;
      #pragma unroll
      for (int nt4 = 0; nt4 < 4; ++nt4)
        #pragma unroll
        for (int r = 0; r < 4; ++r) {
          float pv = __builtin_amdgcn_exp2f(__builtin_fmaf(z[nt4][r], SCALE2, -ms));
          z[nt4][r] = pv;
          ps += pv;
        }
      ps += __shfl_xor(ps, 16);
      ps += __shfl_xor(ps, 32);
      l_run += ps;

      bf16* pbw = &Pb[wave][0];
      #pragma unroll
      for (int nt4 = 0; nt4 < 4; ++nt4) {
        bf16x4 pk = { (bf16)z[nt4][0], (bf16)z[nt4][1], (bf16)z[nt4][2], (bf16)z[nt4][3] };
        *(bf16x4*)((char*)pbw + ((l15 * 128 + nt4 * 32 + l4 * 8) ^ ((l15 & 7) << 4))) = pk;
      }

      // ---- O^T += V^T P^T (this half) ----
      const bf16* vt = &VTs[cur][hf][0];
      #pragma unroll
      for (int kk = 0; kk < 2; ++kk) {
        bf16x8 pf = *(const bf16x8*)((const char*)pbw +
            ((l15 * 128 + kk * 64 + l4 * 16) ^ ((l15 & 7) << 4)));
        #pragma unroll
        for (int dt = 0; dt < 4; ++dt) {
          bf16x8 vf = *(const bf16x8*)((const char*)vt +
              (((dt * 16 + l15) * 128 + (kk * 32 + l4 * 8) * 2) ^ ((l15 & 7) << 4)));
          oacc[dt] = __builtin_amdgcn_mfma_f32_16x16x32_bf16(vf, pf, oacc[dt], 0, 0, 0);
        }
      }
    }

    if (has_next) {
      // write next V into the non-read buffer (its readers retired at the
      // previous tile-end barrier) -> only ONE barrier per tile needed.
      *(bf16x8*)((char*)&VTs[cur ^ 1][0][0] + vwoff) = vr0;
      *(bf16x8*)((char*)&VTs[cur ^ 1][1][0] + vwoff) = vr1;
      __syncthreads();   // publishes VTs[cur^1], retires Kb[cur^1] glds
      cur ^= 1;
    }
  }

  // ---- epilogue: O^T -> y. q = qbase+l15, d = dt*16+l4*4+r ----
  {
    float linv = __builtin_amdgcn_rcpf(l_run);
    bf16* yp = y + ((size_t)b * T_SEQ + qbase + l15) * DIM + h * HD + l4 * 4;
    #pragma unroll
    for (int dt = 0; dt < 4; ++dt) {
      bf16x4 ov = { (bf16)(oacc[dt][0] * linv), (bf16)(oacc[dt][1] * linv),
                    (bf16)(oacc[dt][2] * linv), (bf16)(oacc[dt][3] * linv) };
      *(bf16x4*)(yp + dt * 16) = ov;
    }
  }
}

// ---------------- launch ----------------
extern "C" void kernel_launch(void* const* d_in, const int* in_sizes, int n_in,
                              void* d_out, int out_size, void* d_ws, size_t ws_size,
                              hipStream_t stream) {
  const float* x    = (const float*)d_in[0];
  const float* cosb = (const float*)d_in[1];
  const float* sinb = (const float*)d_in[2];
  const float* wq   = (const float*)d_in[3];
  const float* wk   = (const float*)d_in[4];
  const float* wv   = (const float*)d_in[5];
  const float* wo   = (const float*)d_in[6];
  float* out = (float*)d_out;

  bf16* xb   = (bf16*)d_ws;                           // 4096*2048
  bf16* wqkv = xb + (size_t)MROWS * DIM;              // 3072*2048
  bf16* wob  = wqkv + (size_t)QKV_N * DIM;            // 2048*2048
  bf16* qkv  = wob + (size_t)DIM * DIM;               // 4096*3072
  bf16* y    = qkv + (size_t)MROWS * QKV_N;           // 4096*2048

  // fused casts (one launch)
  cast_all_kernel<<<2048, 256, 0, stream>>>(x, wq, wk, wv, wo, xb, wqkv, wob);

  // QKV projection: M=4096, N=3072, K=2048 -> BM=256: 384 blocks (reverted to R15)
  gemm256<bf16><<<384, 512, 0, stream>>>(xb, wqkv, qkv, QKV_N, DIM, 384 / 8);

  // RoPE on q,k
  rope_kernel<<<(MROWS * 160) / 256, 256, 0, stream>>>(qkv, cosb, sinb);

  // attention: KVBLK=128, VTs dbuf, ONE barrier per kv-tile
  attn_kernel<<<dim3(NH, 16, 2), 512, 0, stream>>>(qkv, y);

  // output projection: M=4096, N=2048, K=2048 -> 256 blocks
  gemm256<float><<<256, 512, 0, stream>>>(y, wob, out, DIM, DIM, 256 / 8);
}

// Round 18
// 182.035 us; speedup vs baseline: 1.0383x; 1.0172x over previous
//
#include <hip/hip_runtime.h>

typedef __bf16 bf16;
typedef __attribute__((ext_vector_type(8))) __bf16 bf16x8;
typedef __attribute__((ext_vector_type(4))) __bf16 bf16x4;
typedef __attribute__((ext_vector_type(4))) float f32x4;

constexpr int T_SEQ = 2048;
constexpr int DIM   = 2048;
constexpr int NH    = 32;
constexpr int NKV   = 8;
constexpr int HD    = 64;
constexpr int QKV_N = DIM + 2 * NKV * HD;   // 3072
constexpr int MROWS = 2 * T_SEQ;            // 4096 (B*T)

// ---------------- fused cast: x -> xb, wq|wk|wv -> wqkv, wo -> wob ----------------
__global__ void cast_all_kernel(const float* __restrict__ x,
                                const float* __restrict__ wq, const float* __restrict__ wk,
                                const float* __restrict__ wv, const float* __restrict__ wo,
                                bf16* __restrict__ xb, bf16* __restrict__ wqkv,
                                bf16* __restrict__ wob) {
  int stride = gridDim.x * blockDim.x;
  for (int g = blockIdx.x * blockDim.x + threadIdx.x; g < 4718592; g += stride) {
    const float* src; bf16* dst; int off;
    if (g < 2097152)      { src = x;  dst = xb;             off = g; }
    else if (g < 3145728) { src = wq; dst = wqkv;           off = g - 2097152; }
    else if (g < 3407872) { src = wk; dst = wqkv + 4194304; off = g - 3145728; }
    else if (g < 3670016) { src = wv; dst = wqkv + 5242880; off = g - 3407872; }
    else                  { src = wo; dst = wob;            off = g - 3670016; }
    float4 v = *(const float4*)(src + (size_t)off * 4);
    bf16x4 o = { (bf16)v.x, (bf16)v.y, (bf16)v.z, (bf16)v.w };
    *(bf16x4*)(dst + (size_t)off * 4) = o;
  }
}

// ---------------- GEMM (BM=256, 3-deep ring, vmcnt(6)) + optional fused RoPE ----------------
// ROPE: applied in the epilogue to blocks with bn < 2560 (q|k columns; v
// columns and out-proj skip). Rotation pair (2i,2i+1) = adjacent lanes ->
// 1 shfl_xor + 2 fma + 2 table loads per element, on f32 acc before bf16 cast.
template <typename OutT, bool ROPE>
__global__ __launch_bounds__(512) void gemm256(const bf16* __restrict__ A,
                                               const bf16* __restrict__ W,
                                               OutT* __restrict__ C,
                                               int N, int K, int cpx,
                                               const float* __restrict__ cs,
                                               const float* __restrict__ sn) {
  constexpr int BM = 256, BN = 128, BK = 64;
  __shared__ __attribute__((aligned(16))) bf16 Ab[3][BM * BK];
  __shared__ __attribute__((aligned(16))) bf16 Bb[3][BN * BK];
  const int tid = threadIdx.x, lane = tid & 63, wave = tid >> 6;
  const int l15 = lane & 15, l4 = lane >> 4;
  const int orig = blockIdx.x;
  const int wg = (orig & 7) * cpx + (orig >> 3);   // XCD chunking (nwg % 8 == 0)
  const int bm = (wg & 15) * BM;                   // M/256 == 16
  const int bn = (wg >> 4) * BN;                   // bn-major
  const int wm = (wave >> 1) * 64, wn = (wave & 1) * 64;

  f32x4 acc[4][4] = {};

  const int NT = K / BK;
  auto stage = [&](int s, int k0) {
    #pragma unroll
    for (int i = 0; i < 4; ++i) {
      int c = i * 512 + tid;
      int row = c >> 3;
      int gc = ((c & 7) ^ (row & 7)) << 3;
      __builtin_amdgcn_global_load_lds(
          (const __attribute__((address_space(1))) unsigned int*)(A + (size_t)(bm + row) * K + k0 + gc),
          (__attribute__((address_space(3))) unsigned int*)(&Ab[s][0] + c * 8), 16, 0, 0);
    }
    #pragma unroll
    for (int i = 0; i < 2; ++i) {
      int c = i * 512 + tid;
      int row = c >> 3;
      int gc = ((c & 7) ^ (row & 7)) << 3;
      __builtin_amdgcn_global_load_lds(
          (const __attribute__((address_space(1))) unsigned int*)(W + (size_t)(bn + row) * K + k0 + gc),
          (__attribute__((address_space(3))) unsigned int*)(&Bb[s][0] + c * 8), 16, 0, 0);
    }
  };

  stage(0, 0);
  stage(1, BK);

  int d = 0;
  for (int t = 0; t < NT; ++t) {
    if (t + 1 < NT) { asm volatile("s_waitcnt vmcnt(6)" ::: "memory"); }
    else            { asm volatile("s_waitcnt vmcnt(0)" ::: "memory"); }
    __builtin_amdgcn_s_barrier();

    bf16x8 af[2][4], bfr[2][4];
    #pragma unroll
    for (int kk = 0; kk < 2; ++kk) {
      #pragma unroll
      for (int mi = 0; mi < 4; ++mi) {
        int row = wm + mi * 16 + l15;
        af[kk][mi] = *(const bf16x8*)((const char*)&Ab[d][0] + row * 128 +
                                      (((kk * 4 + l4) ^ (row & 7)) << 4));
      }
      #pragma unroll
      for (int ni = 0; ni < 4; ++ni) {
        int row = wn + ni * 16 + l15;
        bfr[kk][ni] = *(const bf16x8*)((const char*)&Bb[d][0] + row * 128 +
                                       (((kk * 4 + l4) ^ (row & 7)) << 4));
      }
    }

    if (t + 2 < NT) {
      int s = d + 2; if (s >= 3) s -= 3;
      stage(s, (t + 2) * BK);
    }

    __builtin_amdgcn_s_setprio(1);
    #pragma unroll
    for (int kk = 0; kk < 2; ++kk)
      #pragma unroll
      for (int mi = 0; mi < 4; ++mi)
        #pragma unroll
        for (int ni = 0; ni < 4; ++ni)
          acc[mi][ni] = __builtin_amdgcn_mfma_f32_16x16x32_bf16(af[kk][mi], bfr[kk][ni],
                                                                acc[mi][ni], 0, 0, 0);
    __builtin_amdgcn_s_setprio(0);

    ++d; if (d == 3) d = 0;
  }

  // ---- epilogue (+ fused RoPE for q/k blocks) ----
  if constexpr (ROPE) {
    if (bn < 2560) {   // q|k region: whole block uniform (2560 % 128 == 0)
      const bool odd = (l15 & 1);
      #pragma unroll
      for (int ni = 0; ni < 4; ++ni) {
        int col = bn + wn + ni * 16 + l15;
        int ip = (col & 63) >> 1;            // rotation index within head
        #pragma unroll
        for (int mi = 0; mi < 4; ++mi) {
          int row0 = wm + mi * 16 + l4 * 4;  // block-local; t = (bm+row) & 2047
          #pragma unroll
          for (int r = 0; r < 4; ++r) {
            int tpos = (bm + row0 + r) & (T_SEQ - 1);
            float c = cs[tpos * 32 + ip];
            float s = sn[tpos * 32 + ip];
            float a = acc[mi][ni][r];
            float p = __shfl_xor(a, 1);
            acc[mi][ni][r] = odd ? (p * s + a * c) : (a * c - p * s);
          }
        }
      }
    }
  }

  #pragma unroll
  for (int mi = 0; mi < 4; ++mi)
    #pragma unroll
    for (int ni = 0; ni < 4; ++ni) {
      size_t row = (size_t)bm + wm + mi * 16 + l4 * 4;
      int col = bn + wn + ni * 16 + l15;
      #pragma unroll
      for (int r = 0; r < 4; ++r)
        C[(row + r) * N + col] = (OutT)acc[mi][ni][r];
    }
}

// ---------------- Flash attention, causal GQA (unchanged from R17) ----------------
__global__ __launch_bounds__(512, 2) void attn_kernel(const bf16* __restrict__ qkv,
                                                      bf16* __restrict__ y) {
  const int h = blockIdx.x, b = blockIdx.z;
  const int strip = 15 - blockIdx.y;              // longest-first
  const int g = h >> 2;
  const int tid = threadIdx.x, lane = tid & 63, wave = tid >> 6;
  const int l15 = lane & 15, l4 = lane >> 4;
  const int qbase = strip * 128 + wave * 16;

  __shared__ __attribute__((aligned(16))) bf16 Kb[2][128 * 64];    // [kv][d], swz, dbuf
  __shared__ __attribute__((aligned(16))) bf16 VTs[2][2][64 * 64]; // [buf][half][d][kv], swz
  __shared__ __attribute__((aligned(16))) bf16 Pb[8][16 * 64];     // per-wave [q][kv], swz

  constexpr float SCALE2 = 0.125f * 1.44269504088896f;
  constexpr float THR_RAW = 8.0f / SCALE2;
  constexpr int VOFF = DIM + NKV * HD;

  bf16x8 qf[2];
  {
    const bf16* qp = qkv + ((size_t)b * T_SEQ + qbase + l15) * QKV_N + h * HD + l4 * 8;
    qf[0] = *(const bf16x8*)(qp);
    qf[1] = *(const bf16x8*)(qp + 32);
  }

  f32x4 oacc[4] = {};
  float m_run = -INFINITY, l_run = 0.f;
  const int qg = qbase + l15;

  const int nt = strip + 1;                 // 128-kv tiles
  const size_t kvbase = (size_t)b * T_SEQ;
  const int vwoff = ((lane * 128 + wave * 16) ^ ((lane & 7) << 4));  // VTs write slot

  // ---- prologue: K tile0 -> Kb[0]; V tile0 halves -> VTs[0] ----
  {
    #pragma unroll
    for (int i = 0; i < 2; ++i) {
      int chunk = i * 512 + tid;
      int row = chunk >> 3;
      int csrc = ((chunk & 7) << 3) ^ ((row & 7) << 3);
      __builtin_amdgcn_global_load_lds(
          (const __attribute__((address_space(1))) unsigned int*)
              (qkv + (kvbase + row) * QKV_N + DIM + g * HD + csrc),
          (__attribute__((address_space(3))) unsigned int*)(&Kb[0][0] + chunk * 8), 16, 0, 0);
    }
    #pragma unroll
    for (int hf = 0; hf < 2; ++hf) {
      const bf16* vp = qkv + (kvbase + hf * 64 + wave * 8) * QKV_N + VOFF + g * HD + lane;
      bf16x8 vr;
      #pragma unroll
      for (int j = 0; j < 8; ++j) vr[j] = vp[(size_t)j * QKV_N];
      *(bf16x8*)((char*)&VTs[0][hf][0] + vwoff) = vr;
    }
    asm volatile("s_waitcnt vmcnt(0)" ::: "memory");
    __syncthreads();
  }

  int cur = 0;
  for (int kt = 0; kt < nt; ++kt) {
    const bool has_next = (kt + 1) < nt;
    bf16x8 vr0, vr1;
    if (has_next) {
      #pragma unroll
      for (int i = 0; i < 2; ++i) {
        int chunk = i * 512 + tid;
        int row = chunk >> 3;
        int csrc = ((chunk & 7) << 3) ^ ((row & 7) << 3);
        __builtin_amdgcn_global_load_lds(
            (const __attribute__((address_space(1))) unsigned int*)
                (qkv + (kvbase + (kt + 1) * 128 + row) * QKV_N + DIM + g * HD + csrc),
            (__attribute__((address_space(3))) unsigned int*)(&Kb[cur ^ 1][0] + chunk * 8), 16, 0, 0);
      }
      const bf16* vp0 = qkv + (kvbase + (kt + 1) * 128 + wave * 8) * QKV_N + VOFF + g * HD + lane;
      const bf16* vp1 = vp0 + (size_t)64 * QKV_N;
      #pragma unroll
      for (int j = 0; j < 8; ++j) vr0[j] = vp0[(size_t)j * QKV_N];
      #pragma unroll
      for (int j = 0; j < 8; ++j) vr1[j] = vp1[(size_t)j * QKV_N];
    }

    const bf16* kb = &Kb[cur][0];
    const bool diag = (kt == strip);

    #pragma unroll
    for (int hf = 0; hf < 2; ++hf) {
      if (diag && hf == 1 && wave < 4) continue;   // fully-masked upper half

      f32x4 z[4];
      #pragma unroll
      for (int nt4 = 0; nt4 < 4; ++nt4) z[nt4] = (f32x4){0.f, 0.f, 0.f, 0.f};
      #pragma unroll
      for (int nt4 = 0; nt4 < 4; ++nt4)
        #pragma unroll
        for (int kk = 0; kk < 2; ++kk) {
          bf16x8 kf = *(const bf16x8*)((const char*)kb +
              (((hf * 64 + nt4 * 16 + l15) * 128 + (kk * 32 + l4 * 8) * 2) ^ ((l15 & 7) << 4)));
          z[nt4] = __builtin_amdgcn_mfma_f32_16x16x32_bf16(kf, qf[kk], z[nt4], 0, 0, 0);
        }

      if (diag) {
        #pragma unroll
        for (int nt4 = 0; nt4 < 4; ++nt4)
          #pragma unroll
          for (int r = 0; r < 4; ++r)
            if (kt * 128 + hf * 64 + nt4 * 16 + l4 * 4 + r > qg) z[nt4][r] = -INFINITY;
      }

      float vm = z[0][0];
      #pragma unroll
      for (int nt4 = 0; nt4 < 4; ++nt4)
        #pragma unroll
        for (int r = 0; r < 4; ++r) vm = fmaxf(vm, z[nt4][r]);
      vm = fmaxf(vm, __shfl_xor(vm, 16));
      vm = fmaxf(vm, __shfl_xor(vm, 32));

      if (!__all(vm - m_run <= THR_RAW)) {
        float mnew = fmaxf(m_run, vm);
        float alpha = __builtin_amdgcn_exp2f((m_run - mnew) * SCALE2);
        l_run *= alpha;
        #pragma unroll
        for (int dt = 0; dt < 4; ++dt)
          #pragma unroll
          for (int r = 0; r < 4; ++r) oacc[dt][r] *= alpha;
        m_run = mnew;
      }
      const float ms = m_run * SCALE2;

      float ps = 0.f;
      #pragma unroll
      for (int nt4 = 0; nt4 < 4; ++nt4)
        #pragma unroll
        for (int r = 0; r < 4; ++r) {
          float pv = __builtin_amdgcn_exp2f(__builtin_fmaf(z[nt4][r], SCALE2, -ms));
          z[nt4][r] = pv;
          ps += pv;
        }
      ps += __shfl_xor(ps, 16);
      ps += __shfl_xor(ps, 32);
      l_run += ps;

      bf16* pbw = &Pb[wave][0];
      #pragma unroll
      for (int nt4 = 0; nt4 < 4; ++nt4) {
        bf16x4 pk = { (bf16)z[nt4][0], (bf16)z[nt4][1], (bf16)z[nt4][2], (bf16)z[nt4][3] };
        *(bf16x4*)((char*)pbw + ((l15 * 128 + nt4 * 32 + l4 * 8) ^ ((l15 & 7) << 4))) = pk;
      }

      const bf16* vt = &VTs[cur][hf][0];
      #pragma unroll
      for (int kk = 0; kk < 2; ++kk) {
        bf16x8 pf = *(const bf16x8*)((const char*)pbw +
            ((l15 * 128 + kk * 64 + l4 * 16) ^ ((l15 & 7) << 4)));
        #pragma unroll
        for (int dt = 0; dt < 4; ++dt) {
          bf16x8 vf = *(const bf16x8*)((const char*)vt +
              (((dt * 16 + l15) * 128 + (kk * 32 + l4 * 8) * 2) ^ ((l15 & 7) << 4)));
          oacc[dt] = __builtin_amdgcn_mfma_f32_16x16x32_bf16(vf, pf, oacc[dt], 0, 0, 0);
        }
      }
    }

    if (has_next) {
      *(bf16x8*)((char*)&VTs[cur ^ 1][0][0] + vwoff) = vr0;
      *(bf16x8*)((char*)&VTs[cur ^ 1][1][0] + vwoff) = vr1;
      __syncthreads();   // publishes VTs[cur^1], retires Kb[cur^1] glds
      cur ^= 1;
    }
  }

  {
    float linv = __builtin_amdgcn_rcpf(l_run);
    bf16* yp = y + ((size_t)b * T_SEQ + qbase + l15) * DIM + h * HD + l4 * 4;
    #pragma unroll
    for (int dt = 0; dt < 4; ++dt) {
      bf16x4 ov = { (bf16)(oacc[dt][0] * linv), (bf16)(oacc[dt][1] * linv),
                    (bf16)(oacc[dt][2] * linv), (bf16)(oacc[dt][3] * linv) };
      *(bf16x4*)(yp + dt * 16) = ov;
    }
  }
}

// ---------------- launch ----------------
extern "C" void kernel_launch(void* const* d_in, const int* in_sizes, int n_in,
                              void* d_out, int out_size, void* d_ws, size_t ws_size,
                              hipStream_t stream) {
  const float* x    = (const float*)d_in[0];
  const float* cosb = (const float*)d_in[1];
  const float* sinb = (const float*)d_in[2];
  const float* wq   = (const float*)d_in[3];
  const float* wk   = (const float*)d_in[4];
  const float* wv   = (const float*)d_in[5];
  const float* wo   = (const float*)d_in[6];
  float* out = (float*)d_out;

  bf16* xb   = (bf16*)d_ws;                           // 4096*2048
  bf16* wqkv = xb + (size_t)MROWS * DIM;              // 3072*2048
  bf16* wob  = wqkv + (size_t)QKV_N * DIM;            // 2048*2048
  bf16* qkv  = wob + (size_t)DIM * DIM;               // 4096*3072
  bf16* y    = qkv + (size_t)MROWS * QKV_N;           // 4096*2048

  // fused casts (one launch)
  cast_all_kernel<<<2048, 256, 0, stream>>>(x, wq, wk, wv, wo, xb, wqkv, wob);

  // QKV projection + fused RoPE: M=4096, N=3072, K=2048 -> 384 blocks
  gemm256<bf16, true><<<384, 512, 0, stream>>>(xb, wqkv, qkv, QKV_N, DIM, 384 / 8, cosb, sinb);

  // attention: KVBLK=128, VTs dbuf, one barrier per kv-tile
  attn_kernel<<<dim3(NH, 16, 2), 512, 0, stream>>>(qkv, y);

  // output projection: M=4096, N=2048, K=2048 -> 256 blocks
  gemm256<float, false><<<256, 512, 0, stream>>>(y, wob, out, DIM, DIM, 256 / 8, nullptr, nullptr);
}

// Round 19
// 181.303 us; speedup vs baseline: 1.0425x; 1.0040x over previous
//
#include <hip/hip_runtime.h>

typedef __bf16 bf16;
typedef __attribute__((ext_vector_type(8))) __bf16 bf16x8;
typedef __attribute__((ext_vector_type(4))) __bf16 bf16x4;
typedef __attribute__((ext_vector_type(4))) float f32x4;

constexpr int T_SEQ = 2048;
constexpr int DIM   = 2048;
constexpr int NH    = 32;
constexpr int NKV   = 8;
constexpr int HD    = 64;
constexpr int QKV_N = DIM + 2 * NKV * HD;   // 3072
constexpr int MROWS = 2 * T_SEQ;            // 4096 (B*T)

// ---------------- fused cast: x -> xb, wq|wk|wv -> wqkv, wo -> wob ----------------
__global__ void cast_all_kernel(const float* __restrict__ x,
                                const float* __restrict__ wq, const float* __restrict__ wk,
                                const float* __restrict__ wv, const float* __restrict__ wo,
                                bf16* __restrict__ xb, bf16* __restrict__ wqkv,
                                bf16* __restrict__ wob) {
  int stride = gridDim.x * blockDim.x;
  for (int g = blockIdx.x * blockDim.x + threadIdx.x; g < 4718592; g += stride) {
    const float* src; bf16* dst; int off;
    if (g < 2097152)      { src = x;  dst = xb;             off = g; }
    else if (g < 3145728) { src = wq; dst = wqkv;           off = g - 2097152; }
    else if (g < 3407872) { src = wk; dst = wqkv + 4194304; off = g - 3145728; }
    else if (g < 3670016) { src = wv; dst = wqkv + 5242880; off = g - 3407872; }
    else                  { src = wo; dst = wob;            off = g - 3670016; }
    float4 v = *(const float4*)(src + (size_t)off * 4);
    bf16x4 o = { (bf16)v.x, (bf16)v.y, (bf16)v.z, (bf16)v.w };
    *(bf16x4*)(dst + (size_t)off * 4) = o;
  }
}

// ---------------- GEMM (BM=256, 3-deep ring, vmcnt(6)) + optional fused RoPE ----------------
template <typename OutT, bool ROPE>
__global__ __launch_bounds__(512) void gemm256(const bf16* __restrict__ A,
                                               const bf16* __restrict__ W,
                                               OutT* __restrict__ C,
                                               int N, int K, int cpx,
                                               const float* __restrict__ cs,
                                               const float* __restrict__ sn) {
  constexpr int BM = 256, BN = 128, BK = 64;
  __shared__ __attribute__((aligned(16))) bf16 Ab[3][BM * BK];
  __shared__ __attribute__((aligned(16))) bf16 Bb[3][BN * BK];
  const int tid = threadIdx.x, lane = tid & 63, wave = tid >> 6;
  const int l15 = lane & 15, l4 = lane >> 4;
  const int orig = blockIdx.x;
  const int wg = (orig & 7) * cpx + (orig >> 3);   // XCD chunking (nwg % 8 == 0)
  const int bm = (wg & 15) * BM;                   // M/256 == 16
  const int bn = (wg >> 4) * BN;                   // bn-major
  const int wm = (wave >> 1) * 64, wn = (wave & 1) * 64;

  f32x4 acc[4][4] = {};

  const int NT = K / BK;
  auto stage = [&](int s, int k0) {
    #pragma unroll
    for (int i = 0; i < 4; ++i) {
      int c = i * 512 + tid;
      int row = c >> 3;
      int gc = ((c & 7) ^ (row & 7)) << 3;
      __builtin_amdgcn_global_load_lds(
          (const __attribute__((address_space(1))) unsigned int*)(A + (size_t)(bm + row) * K + k0 + gc),
          (__attribute__((address_space(3))) unsigned int*)(&Ab[s][0] + c * 8), 16, 0, 0);
    }
    #pragma unroll
    for (int i = 0; i < 2; ++i) {
      int c = i * 512 + tid;
      int row = c >> 3;
      int gc = ((c & 7) ^ (row & 7)) << 3;
      __builtin_amdgcn_global_load_lds(
          (const __attribute__((address_space(1))) unsigned int*)(W + (size_t)(bn + row) * K + k0 + gc),
          (__attribute__((address_space(3))) unsigned int*)(&Bb[s][0] + c * 8), 16, 0, 0);
    }
  };

  stage(0, 0);
  stage(1, BK);

  int d = 0;
  for (int t = 0; t < NT; ++t) {
    if (t + 1 < NT) { asm volatile("s_waitcnt vmcnt(6)" ::: "memory"); }
    else            { asm volatile("s_waitcnt vmcnt(0)" ::: "memory"); }
    __builtin_amdgcn_s_barrier();

    bf16x8 af[2][4], bfr[2][4];
    #pragma unroll
    for (int kk = 0; kk < 2; ++kk) {
      #pragma unroll
      for (int mi = 0; mi < 4; ++mi) {
        int row = wm + mi * 16 + l15;
        af[kk][mi] = *(const bf16x8*)((const char*)&Ab[d][0] + row * 128 +
                                      (((kk * 4 + l4) ^ (row & 7)) << 4));
      }
      #pragma unroll
      for (int ni = 0; ni < 4; ++ni) {
        int row = wn + ni * 16 + l15;
        bfr[kk][ni] = *(const bf16x8*)((const char*)&Bb[d][0] + row * 128 +
                                       (((kk * 4 + l4) ^ (row & 7)) << 4));
      }
    }

    if (t + 2 < NT) {
      int s = d + 2; if (s >= 3) s -= 3;
      stage(s, (t + 2) * BK);
    }

    __builtin_amdgcn_s_setprio(1);
    #pragma unroll
    for (int kk = 0; kk < 2; ++kk)
      #pragma unroll
      for (int mi = 0; mi < 4; ++mi)
        #pragma unroll
        for (int ni = 0; ni < 4; ++ni)
          acc[mi][ni] = __builtin_amdgcn_mfma_f32_16x16x32_bf16(af[kk][mi], bfr[kk][ni],
                                                                acc[mi][ni], 0, 0, 0);
    __builtin_amdgcn_s_setprio(0);

    ++d; if (d == 3) d = 0;
  }

  // ---- epilogue (+ fused RoPE for q/k blocks) ----
  if constexpr (ROPE) {
    if (bn < 2560) {   // q|k region: whole block uniform (2560 % 128 == 0)
      const bool odd = (l15 & 1);
      #pragma unroll
      for (int ni = 0; ni < 4; ++ni) {
        int col = bn + wn + ni * 16 + l15;
        int ip = (col & 63) >> 1;            // rotation index within head
        #pragma unroll
        for (int mi = 0; mi < 4; ++mi) {
          int row0 = wm + mi * 16 + l4 * 4;
          #pragma unroll
          for (int r = 0; r < 4; ++r) {
            int tpos = (bm + row0 + r) & (T_SEQ - 1);
            float c = cs[tpos * 32 + ip];
            float s = sn[tpos * 32 + ip];
            float a = acc[mi][ni][r];
            float p = __shfl_xor(a, 1);
            acc[mi][ni][r] = odd ? (p * s + a * c) : (a * c - p * s);
          }
        }
      }
    }
  }

  #pragma unroll
  for (int mi = 0; mi < 4; ++mi)
    #pragma unroll
    for (int ni = 0; ni < 4; ++ni) {
      size_t row = (size_t)bm + wm + mi * 16 + l4 * 4;
      int col = bn + wn + ni * 16 + l15;
      #pragma unroll
      for (int r = 0; r < 4; ++r)
        C[(row + r) * N + col] = (OutT)acc[mi][ni][r];
    }
}

// ---------------- Flash attention, causal GQA ----------------
// R18 structure + two VALU cuts: (1) row-sum l via ones-MFMA (lane-local in
// lacc, deletes 32 adds + 2 shfl per tile); (2) max3-tree row max (8 ops,
// shallow) instead of 15-op serial fmax chain.
__global__ __launch_bounds__(512, 2) void attn_kernel(const bf16* __restrict__ qkv,
                                                      bf16* __restrict__ y) {
  const int h = blockIdx.x, b = blockIdx.z;
  const int strip = 15 - blockIdx.y;              // longest-first
  const int g = h >> 2;
  const int tid = threadIdx.x, lane = tid & 63, wave = tid >> 6;
  const int l15 = lane & 15, l4 = lane >> 4;
  const int qbase = strip * 128 + wave * 16;

  __shared__ __attribute__((aligned(16))) bf16 Kb[2][128 * 64];    // [kv][d], swz, dbuf
  __shared__ __attribute__((aligned(16))) bf16 VTs[2][2][64 * 64]; // [buf][half][d][kv], swz
  __shared__ __attribute__((aligned(16))) bf16 Pb[8][16 * 64];     // per-wave [q][kv], swz

  constexpr float SCALE2 = 0.125f * 1.44269504088896f;
  constexpr float THR_RAW = 8.0f / SCALE2;
  constexpr int VOFF = DIM + NKV * HD;

  const bf16 one1 = (bf16)1.0f;
  const bf16x8 ones = { one1, one1, one1, one1, one1, one1, one1, one1 };

  bf16x8 qf[2];
  {
    const bf16* qp = qkv + ((size_t)b * T_SEQ + qbase + l15) * QKV_N + h * HD + l4 * 8;
    qf[0] = *(const bf16x8*)(qp);
    qf[1] = *(const bf16x8*)(qp + 32);
  }

  f32x4 oacc[4] = {};
  f32x4 lacc = {};                          // row-sum accumulator (ones-MFMA)
  float m_run = -INFINITY;
  const int qg = qbase + l15;

  const int nt = strip + 1;                 // 128-kv tiles
  const size_t kvbase = (size_t)b * T_SEQ;
  const int vwoff = ((lane * 128 + wave * 16) ^ ((lane & 7) << 4));  // VTs write slot

  // ---- prologue: K tile0 -> Kb[0]; V tile0 halves -> VTs[0] ----
  {
    #pragma unroll
    for (int i = 0; i < 2; ++i) {
      int chunk = i * 512 + tid;
      int row = chunk >> 3;
      int csrc = ((chunk & 7) << 3) ^ ((row & 7) << 3);
      __builtin_amdgcn_global_load_lds(
          (const __attribute__((address_space(1))) unsigned int*)
              (qkv + (kvbase + row) * QKV_N + DIM + g * HD + csrc),
          (__attribute__((address_space(3))) unsigned int*)(&Kb[0][0] + chunk * 8), 16, 0, 0);
    }
    #pragma unroll
    for (int hf = 0; hf < 2; ++hf) {
      const bf16* vp = qkv + (kvbase + hf * 64 + wave * 8) * QKV_N + VOFF + g * HD + lane;
      bf16x8 vr;
      #pragma unroll
      for (int j = 0; j < 8; ++j) vr[j] = vp[(size_t)j * QKV_N];
      *(bf16x8*)((char*)&VTs[0][hf][0] + vwoff) = vr;
    }
    asm volatile("s_waitcnt vmcnt(0)" ::: "memory");
    __syncthreads();
  }

  int cur = 0;
  for (int kt = 0; kt < nt; ++kt) {
    const bool has_next = (kt + 1) < nt;
    bf16x8 vr0, vr1;
    if (has_next) {
      #pragma unroll
      for (int i = 0; i < 2; ++i) {
        int chunk = i * 512 + tid;
        int row = chunk >> 3;
        int csrc = ((chunk & 7) << 3) ^ ((row & 7) << 3);
        __builtin_amdgcn_global_load_lds(
            (const __attribute__((address_space(1))) unsigned int*)
                (qkv + (kvbase + (kt + 1) * 128 + row) * QKV_N + DIM + g * HD + csrc),
            (__attribute__((address_space(3))) unsigned int*)(&Kb[cur ^ 1][0] + chunk * 8), 16, 0, 0);
      }
      const bf16* vp0 = qkv + (kvbase + (kt + 1) * 128 + wave * 8) * QKV_N + VOFF + g * HD + lane;
      const bf16* vp1 = vp0 + (size_t)64 * QKV_N;
      #pragma unroll
      for (int j = 0; j < 8; ++j) vr0[j] = vp0[(size_t)j * QKV_N];
      #pragma unroll
      for (int j = 0; j < 8; ++j) vr1[j] = vp1[(size_t)j * QKV_N];
    }

    const bf16* kb = &Kb[cur][0];
    const bool diag = (kt == strip);

    #pragma unroll
    for (int hf = 0; hf < 2; ++hf) {
      if (diag && hf == 1 && wave < 4) continue;   // fully-masked upper half

      // ---- S^T = K Q^T : z[nt4], lane = (q=l15, k=hf*64+nt4*16+l4*4+r), RAW ----
      f32x4 z[4];
      #pragma unroll
      for (int nt4 = 0; nt4 < 4; ++nt4) z[nt4] = (f32x4){0.f, 0.f, 0.f, 0.f};
      #pragma unroll
      for (int nt4 = 0; nt4 < 4; ++nt4)
        #pragma unroll
        for (int kk = 0; kk < 2; ++kk) {
          bf16x8 kf = *(const bf16x8*)((const char*)kb +
              (((hf * 64 + nt4 * 16 + l15) * 128 + (kk * 32 + l4 * 8) * 2) ^ ((l15 & 7) << 4)));
          z[nt4] = __builtin_amdgcn_mfma_f32_16x16x32_bf16(kf, qf[kk], z[nt4], 0, 0, 0);
        }

      if (diag) {
        #pragma unroll
        for (int nt4 = 0; nt4 < 4; ++nt4)
          #pragma unroll
          for (int r = 0; r < 4; ++r)
            if (kt * 128 + hf * 64 + nt4 * 16 + l4 * 4 + r > qg) z[nt4][r] = -INFINITY;
      }

      // ---- row max: max3 tree (8 ops, shallow) + 2 cross-group shfl ----
      float a0 = fmaxf(fmaxf(z[0][0], z[0][1]), z[0][2]);
      float a1 = fmaxf(fmaxf(z[0][3], z[1][0]), z[1][1]);
      float a2 = fmaxf(fmaxf(z[1][2], z[1][3]), z[2][0]);
      float a3 = fmaxf(fmaxf(z[2][1], z[2][2]), z[2][3]);
      float a4 = fmaxf(fmaxf(z[3][0], z[3][1]), z[3][2]);
      float b0 = fmaxf(fmaxf(a0, a1), a2);
      float b1 = fmaxf(fmaxf(a3, a4), z[3][3]);
      float vm = fmaxf(b0, b1);
      vm = fmaxf(vm, __shfl_xor(vm, 16));
      vm = fmaxf(vm, __shfl_xor(vm, 32));

      // ---- defer-max rescale ----
      if (!__all(vm - m_run <= THR_RAW)) {
        float mnew = fmaxf(m_run, vm);
        float alpha = __builtin_amdgcn_exp2f((m_run - mnew) * SCALE2);
        #pragma unroll
        for (int r = 0; r < 4; ++r) lacc[r] *= alpha;
        #pragma unroll
        for (int dt = 0; dt < 4; ++dt)
          #pragma unroll
          for (int r = 0; r < 4; ++r) oacc[dt][r] *= alpha;
        m_run = mnew;
      }
      const float ms = m_run * SCALE2;

      // ---- P = exp2(z*S - ms) in place (row-sum comes from ones-MFMA) ----
      #pragma unroll
      for (int nt4 = 0; nt4 < 4; ++nt4)
        #pragma unroll
        for (int r = 0; r < 4; ++r)
          z[nt4][r] = __builtin_amdgcn_exp2f(__builtin_fmaf(z[nt4][r], SCALE2, -ms));

      bf16* pbw = &Pb[wave][0];
      #pragma unroll
      for (int nt4 = 0; nt4 < 4; ++nt4) {
        bf16x4 pk = { (bf16)z[nt4][0], (bf16)z[nt4][1], (bf16)z[nt4][2], (bf16)z[nt4][3] };
        *(bf16x4*)((char*)pbw + ((l15 * 128 + nt4 * 32 + l4 * 8) ^ ((l15 & 7) << 4))) = pk;
      }

      // ---- O^T += V^T P^T ; lacc += ones * P^T (row-sum) ----
      const bf16* vt = &VTs[cur][hf][0];
      #pragma unroll
      for (int kk = 0; kk < 2; ++kk) {
        bf16x8 pf = *(const bf16x8*)((const char*)pbw +
            ((l15 * 128 + kk * 64 + l4 * 16) ^ ((l15 & 7) << 4)));
        lacc = __builtin_amdgcn_mfma_f32_16x16x32_bf16(ones, pf, lacc, 0, 0, 0);
        #pragma unroll
        for (int dt = 0; dt < 4; ++dt) {
          bf16x8 vf = *(const bf16x8*)((const char*)vt +
              (((dt * 16 + l15) * 128 + (kk * 32 + l4 * 8) * 2) ^ ((l15 & 7) << 4)));
          oacc[dt] = __builtin_amdgcn_mfma_f32_16x16x32_bf16(vf, pf, oacc[dt], 0, 0, 0);
        }
      }
    }

    if (has_next) {
      *(bf16x8*)((char*)&VTs[cur ^ 1][0][0] + vwoff) = vr0;
      *(bf16x8*)((char*)&VTs[cur ^ 1][1][0] + vwoff) = vr1;
      __syncthreads();   // publishes VTs[cur^1], retires Kb[cur^1] glds
      cur ^= 1;
    }
  }

  // ---- epilogue: O^T -> y. q = qbase+l15, d = dt*16+l4*4+r ----
  {
    float linv = __builtin_amdgcn_rcpf(lacc[0]);
    bf16* yp = y + ((size_t)b * T_SEQ + qbase + l15) * DIM + h * HD + l4 * 4;
    #pragma unroll
    for (int dt = 0; dt < 4; ++dt) {
      bf16x4 ov = { (bf16)(oacc[dt][0] * linv), (bf16)(oacc[dt][1] * linv),
                    (bf16)(oacc[dt][2] * linv), (bf16)(oacc[dt][3] * linv) };
      *(bf16x4*)(yp + dt * 16) = ov;
    }
  }
}

// ---------------- launch ----------------
extern "C" void kernel_launch(void* const* d_in, const int* in_sizes, int n_in,
                              void* d_out, int out_size, void* d_ws, size_t ws_size,
                              hipStream_t stream) {
  const float* x    = (const float*)d_in[0];
  const float* cosb = (const float*)d_in[1];
  const float* sinb = (const float*)d_in[2];
  const float* wq   = (const float*)d_in[3];
  const float* wk   = (const float*)d_in[4];
  const float* wv   = (const float*)d_in[5];
  const float* wo   = (const float*)d_in[6];
  float* out = (float*)d_out;

  bf16* xb   = (bf16*)d_ws;                           // 4096*2048
  bf16* wqkv = xb + (size_t)MROWS * DIM;              // 3072*2048
  bf16* wob  = wqkv + (size_t)QKV_N * DIM;            // 2048*2048
  bf16* qkv  = wob + (size_t)DIM * DIM;               // 4096*3072
  bf16* y    = qkv + (size_t)MROWS * QKV_N;           // 4096*2048

  // fused casts (one launch)
  cast_all_kernel<<<2048, 256, 0, stream>>>(x, wq, wk, wv, wo, xb, wqkv, wob);

  // QKV projection + fused RoPE: M=4096, N=3072, K=2048 -> 384 blocks
  gemm256<bf16, true><<<384, 512, 0, stream>>>(xb, wqkv, qkv, QKV_N, DIM, 384 / 8, cosb, sinb);

  // attention: KVBLK=128, VTs dbuf, one barrier per kv-tile
  attn_kernel<<<dim3(NH, 16, 2), 512, 0, stream>>>(qkv, y);

  // output projection: M=4096, N=2048, K=2048 -> 256 blocks
  gemm256<float, false><<<256, 512, 0, stream>>>(y, wob, out, DIM, DIM, 256 / 8, nullptr, nullptr);
}

// Round 20
// 164.886 us; speedup vs baseline: 1.1463x; 1.0996x over previous
//
#include <hip/hip_runtime.h>

typedef __bf16 bf16;
typedef __attribute__((ext_vector_type(8))) __bf16 bf16x8;
typedef __attribute__((ext_vector_type(4))) __bf16 bf16x4;
typedef __attribute__((ext_vector_type(4))) float f32x4;

constexpr int T_SEQ = 2048;
constexpr int DIM   = 2048;
constexpr int NH    = 32;
constexpr int NKV   = 8;
constexpr int HD    = 64;
constexpr int QKV_N = DIM + 2 * NKV * HD;   // 3072
constexpr int MROWS = 2 * T_SEQ;            // 4096 (B*T)

// ---------------- fused cast: x -> xb, wq|wk|wv -> wqkv, wo -> wob ----------------
__global__ void cast_all_kernel(const float* __restrict__ x,
                                const float* __restrict__ wq, const float* __restrict__ wk,
                                const float* __restrict__ wv, const float* __restrict__ wo,
                                bf16* __restrict__ xb, bf16* __restrict__ wqkv,
                                bf16* __restrict__ wob) {
  int stride = gridDim.x * blockDim.x;
  for (int g = blockIdx.x * blockDim.x + threadIdx.x; g < 4718592; g += stride) {
    const float* src; bf16* dst; int off;
    if (g < 2097152)      { src = x;  dst = xb;             off = g; }
    else if (g < 3145728) { src = wq; dst = wqkv;           off = g - 2097152; }
    else if (g < 3407872) { src = wk; dst = wqkv + 4194304; off = g - 3145728; }
    else if (g < 3670016) { src = wv; dst = wqkv + 5242880; off = g - 3407872; }
    else                  { src = wo; dst = wob;            off = g - 3670016; }
    float4 v = *(const float4*)(src + (size_t)off * 4);
    bf16x4 o = { (bf16)v.x, (bf16)v.y, (bf16)v.z, (bf16)v.w };
    *(bf16x4*)(dst + (size_t)off * 4) = o;
  }
}

// rect XCD decode for 256-block 16x16 grids: XCD c gets an 8(bm) x 4(bn) rect.
__device__ inline void rect_decode(int orig, int& bmi, int& bni) {
  int c = orig & 7, i = orig >> 3;          // c = XCD (dispatch round-robin)
  bmi = (c & 1) * 8 + (i & 7);
  bni = (c >> 1) * 4 + (i >> 3);
}

// ---------------- out-proj GEMM: BM=256 BN=128, A ring-3, vmcnt(6) ----------------
__global__ __launch_bounds__(512) void gemm256(const bf16* __restrict__ A,
                                               const bf16* __restrict__ W,
                                               float* __restrict__ C,
                                               int N, int K) {
  constexpr int BM = 256, BN = 128, BK = 64;
  __shared__ __attribute__((aligned(16))) bf16 Ab[3][BM * BK];
  __shared__ __attribute__((aligned(16))) bf16 Bb[3][BN * BK];
  const int tid = threadIdx.x, lane = tid & 63, wave = tid >> 6;
  const int l15 = lane & 15, l4 = lane >> 4;
  int bmi, bni;
  rect_decode(blockIdx.x, bmi, bni);
  const int bm = bmi * BM, bn = bni * BN;
  const int wm = (wave >> 1) * 64, wn = (wave & 1) * 64;

  f32x4 acc[4][4] = {};

  const int NT = K / BK;
  auto stage = [&](int s, int k0) {
    #pragma unroll
    for (int i = 0; i < 4; ++i) {
      int c = i * 512 + tid;
      int row = c >> 3;
      int gc = ((c & 7) ^ (row & 7)) << 3;
      __builtin_amdgcn_global_load_lds(
          (const __attribute__((address_space(1))) unsigned int*)(A + (size_t)(bm + row) * K + k0 + gc),
          (__attribute__((address_space(3))) unsigned int*)(&Ab[s][0] + c * 8), 16, 0, 0);
    }
    #pragma unroll
    for (int i = 0; i < 2; ++i) {
      int c = i * 512 + tid;
      int row = c >> 3;
      int gc = ((c & 7) ^ (row & 7)) << 3;
      __builtin_amdgcn_global_load_lds(
          (const __attribute__((address_space(1))) unsigned int*)(W + (size_t)(bn + row) * K + k0 + gc),
          (__attribute__((address_space(3))) unsigned int*)(&Bb[s][0] + c * 8), 16, 0, 0);
    }
  };

  stage(0, 0);
  stage(1, BK);

  int d = 0;
  for (int t = 0; t < NT; ++t) {
    if (t + 1 < NT) { asm volatile("s_waitcnt vmcnt(6)" ::: "memory"); }
    else            { asm volatile("s_waitcnt vmcnt(0)" ::: "memory"); }
    __builtin_amdgcn_s_barrier();

    bf16x8 af[2][4], bfr[2][4];
    #pragma unroll
    for (int kk = 0; kk < 2; ++kk) {
      #pragma unroll
      for (int mi = 0; mi < 4; ++mi) {
        int row = wm + mi * 16 + l15;
        af[kk][mi] = *(const bf16x8*)((const char*)&Ab[d][0] + row * 128 +
                                      (((kk * 4 + l4) ^ (row & 7)) << 4));
      }
      #pragma unroll
      for (int ni = 0; ni < 4; ++ni) {
        int row = wn + ni * 16 + l15;
        bfr[kk][ni] = *(const bf16x8*)((const char*)&Bb[d][0] + row * 128 +
                                       (((kk * 4 + l4) ^ (row & 7)) << 4));
      }
    }

    if (t + 2 < NT) {
      int s = d + 2; if (s >= 3) s -= 3;
      stage(s, (t + 2) * BK);
    }

    __builtin_amdgcn_s_setprio(1);
    #pragma unroll
    for (int kk = 0; kk < 2; ++kk)
      #pragma unroll
      for (int mi = 0; mi < 4; ++mi)
        #pragma unroll
        for (int ni = 0; ni < 4; ++ni)
          acc[mi][ni] = __builtin_amdgcn_mfma_f32_16x16x32_bf16(af[kk][mi], bfr[kk][ni],
                                                                acc[mi][ni], 0, 0, 0);
    __builtin_amdgcn_s_setprio(0);

    ++d; if (d == 3) d = 0;
  }

  #pragma unroll
  for (int mi = 0; mi < 4; ++mi)
    #pragma unroll
    for (int ni = 0; ni < 4; ++ni) {
      size_t row = (size_t)bm + wm + mi * 16 + l4 * 4;
      int col = bn + wn + ni * 16 + l15;
      #pragma unroll
      for (int r = 0; r < 4; ++r)
        C[(row + r) * N + col] = acc[mi][ni][r];
    }
}

// ---------------- QKV GEMM: BM=256 BN=192 + fused RoPE ----------------
// 256 blocks = ONE exact round (vs 384 = 1.5 rounds). A ring-3 (depth-2,
// 96KB) + B ring-2 (depth-1, 48KB) = 144KB. Issue order per tile: B(t+1)
// then A(t+2); steady-state wait vmcnt(4) (only A(t+1) in flight).
__global__ __launch_bounds__(512, 1) void gemm192(const bf16* __restrict__ A,
                                                  const bf16* __restrict__ W,
                                                  bf16* __restrict__ C,
                                                  const float* __restrict__ cs,
                                                  const float* __restrict__ sn) {
  constexpr int BM = 256, BN = 192, BK = 64, N = QKV_N, K = DIM;
  __shared__ __attribute__((aligned(16))) bf16 Ab[3][BM * BK];
  __shared__ __attribute__((aligned(16))) bf16 Bb[2][BN * BK];
  const int tid = threadIdx.x, lane = tid & 63, wave = tid >> 6;
  const int l15 = lane & 15, l4 = lane >> 4;
  int bmi, bni;
  rect_decode(blockIdx.x, bmi, bni);
  const int bm = bmi * BM, bn = bni * BN;
  const int wm = (wave >> 1) * 64, wn = (wave & 1) * 96;

  f32x4 acc[4][6] = {};

  constexpr int NT = K / BK;   // 32
  auto stageA = [&](int s, int k0) {
    #pragma unroll
    for (int i = 0; i < 4; ++i) {
      int c = i * 512 + tid;
      int row = c >> 3;
      int gc = ((c & 7) ^ (row & 7)) << 3;
      __builtin_amdgcn_global_load_lds(
          (const __attribute__((address_space(1))) unsigned int*)(A + (size_t)(bm + row) * K + k0 + gc),
          (__attribute__((address_space(3))) unsigned int*)(&Ab[s][0] + c * 8), 16, 0, 0);
    }
  };
  auto stageB = [&](int s, int k0) {
    #pragma unroll
    for (int i = 0; i < 3; ++i) {          // 192x64 = 24KB = 3 x 512thr x 16B
      int c = i * 512 + tid;
      int row = c >> 3;
      int gc = ((c & 7) ^ (row & 7)) << 3;
      __builtin_amdgcn_global_load_lds(
          (const __attribute__((address_space(1))) unsigned int*)(W + (size_t)(bn + row) * K + k0 + gc),
          (__attribute__((address_space(3))) unsigned int*)(&Bb[s][0] + c * 8), 16, 0, 0);
    }
  };

  stageA(0, 0);
  stageB(0, 0);
  stageA(1, BK);

  for (int t = 0; t < NT; ++t) {
    const int d3 = t % 3, db = t & 1;
    // queue (oldest->newest): [B(t), A(t+1)] after prior iters; need A(t),B(t).
    if (t + 1 < NT) { asm volatile("s_waitcnt vmcnt(4)" ::: "memory"); }
    else            { asm volatile("s_waitcnt vmcnt(0)" ::: "memory"); }
    __builtin_amdgcn_s_barrier();

    bf16x8 af[2][4], bfr[2][6];
    #pragma unroll
    for (int kk = 0; kk < 2; ++kk) {
      #pragma unroll
      for (int mi = 0; mi < 4; ++mi) {
        int row = wm + mi * 16 + l15;
        af[kk][mi] = *(const bf16x8*)((const char*)&Ab[d3][0] + row * 128 +
                                      (((kk * 4 + l4) ^ (row & 7)) << 4));
      }
      #pragma unroll
      for (int ni = 0; ni < 6; ++ni) {
        int row = wn + ni * 16 + l15;
        bfr[kk][ni] = *(const bf16x8*)((const char*)&Bb[db][0] + row * 128 +
                                       (((kk * 4 + l4) ^ (row & 7)) << 4));
      }
    }

    if (t + 1 < NT) stageB(db ^ 1, (t + 1) * BK);   // old readers retired at this tile's barrier
    if (t + 2 < NT) { int s = d3 + 2; if (s >= 3) s -= 3; stageA(s, (t + 2) * BK); }

    __builtin_amdgcn_s_setprio(1);
    #pragma unroll
    for (int kk = 0; kk < 2; ++kk)
      #pragma unroll
      for (int mi = 0; mi < 4; ++mi)
        #pragma unroll
        for (int ni = 0; ni < 6; ++ni)
          acc[mi][ni] = __builtin_amdgcn_mfma_f32_16x16x32_bf16(af[kk][mi], bfr[kk][ni],
                                                                acc[mi][ni], 0, 0, 0);
    __builtin_amdgcn_s_setprio(0);
  }

  // ---- epilogue: fused RoPE on q|k frags (col < 2560; frag-uniform) ----
  const bool odd = (l15 & 1);
  #pragma unroll
  for (int ni = 0; ni < 6; ++ni) {
    if (bn + wn + ni * 16 < 2560) {
      int col = bn + wn + ni * 16 + l15;
      int ip = (col & 63) >> 1;
      #pragma unroll
      for (int mi = 0; mi < 4; ++mi) {
        int row0 = wm + mi * 16 + l4 * 4;
        #pragma unroll
        for (int r = 0; r < 4; ++r) {
          int tpos = (bm + row0 + r) & (T_SEQ - 1);
          float c = cs[tpos * 32 + ip];
          float s = sn[tpos * 32 + ip];
          float a = acc[mi][ni][r];
          float p = __shfl_xor(a, 1);
          acc[mi][ni][r] = odd ? (p * s + a * c) : (a * c - p * s);
        }
      }
    }
  }

  #pragma unroll
  for (int mi = 0; mi < 4; ++mi)
    #pragma unroll
    for (int ni = 0; ni < 6; ++ni) {
      size_t row = (size_t)bm + wm + mi * 16 + l4 * 4;
      int col = bn + wn + ni * 16 + l15;
      #pragma unroll
      for (int r = 0; r < 4; ++r)
        C[(row + r) * N + col] = (bf16)acc[mi][ni][r];
    }
}

// ---------------- Flash attention, causal GQA (unchanged from R19) ----------------
__global__ __launch_bounds__(512, 2) void attn_kernel(const bf16* __restrict__ qkv,
                                                      bf16* __restrict__ y) {
  const int h = blockIdx.x, b = blockIdx.z;
  const int strip = 15 - blockIdx.y;
  const int g = h >> 2;
  const int tid = threadIdx.x, lane = tid & 63, wave = tid >> 6;
  const int l15 = lane & 15, l4 = lane >> 4;
  const int qbase = strip * 128 + wave * 16;

  __shared__ __attribute__((aligned(16))) bf16 Kb[2][128 * 64];
  __shared__ __attribute__((aligned(16))) bf16 VTs[2][2][64 * 64];
  __shared__ __attribute__((aligned(16))) bf16 Pb[8][16 * 64];

  constexpr float SCALE2 = 0.125f * 1.44269504088896f;
  constexpr float THR_RAW = 8.0f / SCALE2;
  constexpr int VOFF = DIM + NKV * HD;

  const bf16 one1 = (bf16)1.0f;
  const bf16x8 ones = { one1, one1, one1, one1, one1, one1, one1, one1 };

  bf16x8 qf[2];
  {
    const bf16* qp = qkv + ((size_t)b * T_SEQ + qbase + l15) * QKV_N + h * HD + l4 * 8;
    qf[0] = *(const bf16x8*)(qp);
    qf[1] = *(const bf16x8*)(qp + 32);
  }

  f32x4 oacc[4] = {};
  f32x4 lacc = {};
  float m_run = -INFINITY;
  const int qg = qbase + l15;

  const int nt = strip + 1;
  const size_t kvbase = (size_t)b * T_SEQ;
  const int vwoff = ((lane * 128 + wave * 16) ^ ((lane & 7) << 4));

  {
    #pragma unroll
    for (int i = 0; i < 2; ++i) {
      int chunk = i * 512 + tid;
      int row = chunk >> 3;
      int csrc = ((chunk & 7) << 3) ^ ((row & 7) << 3);
      __builtin_amdgcn_global_load_lds(
          (const __attribute__((address_space(1))) unsigned int*)
              (qkv + (kvbase + row) * QKV_N + DIM + g * HD + csrc),
          (__attribute__((address_space(3))) unsigned int*)(&Kb[0][0] + chunk * 8), 16, 0, 0);
    }
    #pragma unroll
    for (int hf = 0; hf < 2; ++hf) {
      const bf16* vp = qkv + (kvbase + hf * 64 + wave * 8) * QKV_N + VOFF + g * HD + lane;
      bf16x8 vr;
      #pragma unroll
      for (int j = 0; j < 8; ++j) vr[j] = vp[(size_t)j * QKV_N];
      *(bf16x8*)((char*)&VTs[0][hf][0] + vwoff) = vr;
    }
    asm volatile("s_waitcnt vmcnt(0)" ::: "memory");
    __syncthreads();
  }

  int cur = 0;
  for (int kt = 0; kt < nt; ++kt) {
    const bool has_next = (kt + 1) < nt;
    bf16x8 vr0, vr1;
    if (has_next) {
      #pragma unroll
      for (int i = 0; i < 2; ++i) {
        int chunk = i * 512 + tid;
        int row = chunk >> 3;
        int csrc = ((chunk & 7) << 3) ^ ((row & 7) << 3);
        __builtin_amdgcn_global_load_lds(
            (const __attribute__((address_space(1))) unsigned int*)
                (qkv + (kvbase + (kt + 1) * 128 + row) * QKV_N + DIM + g * HD + csrc),
            (__attribute__((address_space(3))) unsigned int*)(&Kb[cur ^ 1][0] + chunk * 8), 16, 0, 0);
      }
      const bf16* vp0 = qkv + (kvbase + (kt + 1) * 128 + wave * 8) * QKV_N + VOFF + g * HD + lane;
      const bf16* vp1 = vp0 + (size_t)64 * QKV_N;
      #pragma unroll
      for (int j = 0; j < 8; ++j) vr0[j] = vp0[(size_t)j * QKV_N];
      #pragma unroll
      for (int j = 0; j < 8; ++j) vr1[j] = vp1[(size_t)j * QKV_N];
    }

    const bf16* kb = &Kb[cur][0];
    const bool diag = (kt == strip);

    #pragma unroll
    for (int hf = 0; hf < 2; ++hf) {
      if (diag && hf == 1 && wave < 4) continue;

      f32x4 z[4];
      #pragma unroll
      for (int nt4 = 0; nt4 < 4; ++nt4) z[nt4] = (f32x4){0.f, 0.f, 0.f, 0.f};
      #pragma unroll
      for (int nt4 = 0; nt4 < 4; ++nt4)
        #pragma unroll
        for (int kk = 0; kk < 2; ++kk) {
          bf16x8 kf = *(const bf16x8*)((const char*)kb +
              (((hf * 64 + nt4 * 16 + l15) * 128 + (kk * 32 + l4 * 8) * 2) ^ ((l15 & 7) << 4)));
          z[nt4] = __builtin_amdgcn_mfma_f32_16x16x32_bf16(kf, qf[kk], z[nt4], 0, 0, 0);
        }

      if (diag) {
        #pragma unroll
        for (int nt4 = 0; nt4 < 4; ++nt4)
          #pragma unroll
          for (int r = 0; r < 4; ++r)
            if (kt * 128 + hf * 64 + nt4 * 16 + l4 * 4 + r > qg) z[nt4][r] = -INFINITY;
      }

      float a0 = fmaxf(fmaxf(z[0][0], z[0][1]), z[0][2]);
      float a1 = fmaxf(fmaxf(z[0][3], z[1][0]), z[1][1]);
      float a2 = fmaxf(fmaxf(z[1][2], z[1][3]), z[2][0]);
      float a3 = fmaxf(fmaxf(z[2][1], z[2][2]), z[2][3]);
      float a4 = fmaxf(fmaxf(z[3][0], z[3][1]), z[3][2]);
      float b0 = fmaxf(fmaxf(a0, a1), a2);
      float b1 = fmaxf(fmaxf(a3, a4), z[3][3]);
      float vm = fmaxf(b0, b1);
      vm = fmaxf(vm, __shfl_xor(vm, 16));
      vm = fmaxf(vm, __shfl_xor(vm, 32));

      if (!__all(vm - m_run <= THR_RAW)) {
        float mnew = fmaxf(m_run, vm);
        float alpha = __builtin_amdgcn_exp2f((m_run - mnew) * SCALE2);
        #pragma unroll
        for (int r = 0; r < 4; ++r) lacc[r] *= alpha;
        #pragma unroll
        for (int dt = 0; dt < 4; ++dt)
          #pragma unroll
          for (int r = 0; r < 4; ++r) oacc[dt][r] *= alpha;
        m_run = mnew;
      }
      const float ms = m_run * SCALE2;

      #pragma unroll
      for (int nt4 = 0; nt4 < 4; ++nt4)
        #pragma unroll
        for (int r = 0; r < 4; ++r)
          z[nt4][r] = __builtin_amdgcn_exp2f(__builtin_fmaf(z[nt4][r], SCALE2, -ms));

      bf16* pbw = &Pb[wave][0];
      #pragma unroll
      for (int nt4 = 0; nt4 < 4; ++nt4) {
        bf16x4 pk = { (bf16)z[nt4][0], (bf16)z[nt4][1], (bf16)z[nt4][2], (bf16)z[nt4][3] };
        *(bf16x4*)((char*)pbw + ((l15 * 128 + nt4 * 32 + l4 * 8) ^ ((l15 & 7) << 4))) = pk;
      }

      const bf16* vt = &VTs[cur][hf][0];
      #pragma unroll
      for (int kk = 0; kk < 2; ++kk) {
        bf16x8 pf = *(const bf16x8*)((const char*)pbw +
            ((l15 * 128 + kk * 64 + l4 * 16) ^ ((l15 & 7) << 4)));
        lacc = __builtin_amdgcn_mfma_f32_16x16x32_bf16(ones, pf, lacc, 0, 0, 0);
        #pragma unroll
        for (int dt = 0; dt < 4; ++dt) {
          bf16x8 vf = *(const bf16x8*)((const char*)vt +
              (((dt * 16 + l15) * 128 + (kk * 32 + l4 * 8) * 2) ^ ((l15 & 7) << 4)));
          oacc[dt] = __builtin_amdgcn_mfma_f32_16x16x32_bf16(vf, pf, oacc[dt], 0, 0, 0);
        }
      }
    }

    if (has_next) {
      *(bf16x8*)((char*)&VTs[cur ^ 1][0][0] + vwoff) = vr0;
      *(bf16x8*)((char*)&VTs[cur ^ 1][1][0] + vwoff) = vr1;
      __syncthreads();
      cur ^= 1;
    }
  }

  {
    float linv = __builtin_amdgcn_rcpf(lacc[0]);
    bf16* yp = y + ((size_t)b * T_SEQ + qbase + l15) * DIM + h * HD + l4 * 4;
    #pragma unroll
    for (int dt = 0; dt < 4; ++dt) {
      bf16x4 ov = { (bf16)(oacc[dt][0] * linv), (bf16)(oacc[dt][1] * linv),
                    (bf16)(oacc[dt][2] * linv), (bf16)(oacc[dt][3] * linv) };
      *(bf16x4*)(yp + dt * 16) = ov;
    }
  }
}

// ---------------- launch ----------------
extern "C" void kernel_launch(void* const* d_in, const int* in_sizes, int n_in,
                              void* d_out, int out_size, void* d_ws, size_t ws_size,
                              hipStream_t stream) {
  const float* x    = (const float*)d_in[0];
  const float* cosb = (const float*)d_in[1];
  const float* sinb = (const float*)d_in[2];
  const float* wq   = (const float*)d_in[3];
  const float* wk   = (const float*)d_in[4];
  const float* wv   = (const float*)d_in[5];
  const float* wo   = (const float*)d_in[6];
  float* out = (float*)d_out;

  bf16* xb   = (bf16*)d_ws;                           // 4096*2048
  bf16* wqkv = xb + (size_t)MROWS * DIM;              // 3072*2048
  bf16* wob  = wqkv + (size_t)QKV_N * DIM;            // 2048*2048
  bf16* qkv  = wob + (size_t)DIM * DIM;               // 4096*3072
  bf16* y    = qkv + (size_t)MROWS * QKV_N;           // 4096*2048

  // fused casts (one launch)
  cast_all_kernel<<<2048, 256, 0, stream>>>(x, wq, wk, wv, wo, xb, wqkv, wob);

  // QKV projection + fused RoPE: BM=256 BN=192 -> 16x16 = 256 blocks, one round
  gemm192<<<256, 512, 0, stream>>>(xb, wqkv, qkv, cosb, sinb);

  // attention: KVBLK=128, VTs dbuf, one barrier per kv-tile
  attn_kernel<<<dim3(NH, 16, 2), 512, 0, stream>>>(qkv, y);

  // output projection: BM=256 BN=128 -> 256 blocks, one round
  gemm256<<<256, 512, 0, stream>>>(y, wob, out, DIM, DIM);
}